// Round 1
// baseline (485.299 us; speedup 1.0000x reference)
//
#include <hip/hip_runtime.h>

// ---------------------------------------------------------------------------
// AggMaskStarHead: SOLO-style dynamic mask head, fp32 throughout.
//
// Pipeline:
//  K1 k_gemm_ys : 16x256 GEMM per source at native res (ctx 1x1-conv factored
//                 through the linear resizes)
//  K2 k_feat    : feat[20][16384] = [mask_feat(4); relu(b + y0 + sum bilin(ys))]
//  K3 k_kin     : x2 (32x32) -> kin (24x24) antialiased triangle resize, padded 26x26
//  K4 k_kpconv  : 3x3 conv 256->249 over 24x24 -> kpT[576][249]
//  K5 k_x0r     : x0 (128x128) -> 40x40 antialiased resize, padded 42x42
//  K6 k_cate    : 3x3 conv 256->80 + sigmoid -> cate_pre
//  K7 k_nms     : points_nms -> out[9437184..]
//  K8 k_dyn     : fused 3-layer dynamic MLP + sigmoid -> out[0..9437184)
// ---------------------------------------------------------------------------

// workspace float offsets
#define OFF_Y0   0u           // 16*16384
#define OFF_Y1   262144u      // 16*4096
#define OFF_Y2   327680u      // 16*1024
#define OFF_Y3   344064u      // 16*256
#define OFF_Y4   348160u      // 16*64
#define OFF_FEAT 349184u      // 20*16384
#define OFF_KIN  676864u      // 256*676  (26x26 zero-padded)
#define OFF_KPT  849920u      // 576*249
#define OFF_X0R  993344u      // 256*1764 (42x42 zero-padded)
#define OFF_CATE 1444928u     // 80*1600
// total 1572928 floats = 6.3 MB

#define SEG_ELEMS 9437184     // 576*128*128

__device__ __forceinline__ float sigmoidf_(float x) {
  return 1.0f / (1.0f + __expf(-x));
}

// ---------------- K1: per-source 16x256 GEMMs ------------------------------
__global__ __launch_bounds__(256) void k_gemm_ys(
    const float* __restrict__ x0, const float* __restrict__ x1,
    const float* __restrict__ x2, const float* __restrict__ x3,
    const float* __restrict__ x4, const float* __restrict__ w_ctx,
    float* __restrict__ ws) {
  __shared__ float wl[4096];  // [c][o] layout
  const int b = blockIdx.x, tid = threadIdx.x;
  int s, Q, qb;
  const float* xs;
  float* ys;
  if (b < 64)      { s = 0; xs = x0; ys = ws + OFF_Y0; Q = 16384; qb = b * 256; }
  else if (b < 80) { s = 1; xs = x1; ys = ws + OFF_Y1; Q = 4096;  qb = (b - 64) * 256; }
  else if (b < 84) { s = 2; xs = x2; ys = ws + OFF_Y2; Q = 1024;  qb = (b - 80) * 256; }
  else if (b < 85) { s = 3; xs = x3; ys = ws + OFF_Y3; Q = 256;   qb = 0; }
  else             { s = 4; xs = x4; ys = ws + OFF_Y4; Q = 64;    qb = 0; }
  for (int i = tid; i < 4096; i += 256) {
    const int c = i >> 4, o = i & 15;
    wl[i] = w_ctx[o * 1280 + s * 256 + c];
  }
  __syncthreads();
  const int q = qb + tid;
  if (q < Q) {
    float acc[16];
#pragma unroll
    for (int o = 0; o < 16; ++o) acc[o] = 0.f;
    for (int c = 0; c < 256; ++c) {
      const float v = xs[c * Q + q];
      const float* wc = &wl[c * 16];
#pragma unroll
      for (int o = 0; o < 16; ++o) acc[o] += wc[o] * v;
    }
#pragma unroll
    for (int o = 0; o < 16; ++o) ys[o * Q + q] = acc[o];
  }
}

// ---------------- K2: build feat = [mask_feat; relu(ctx)] ------------------
__global__ __launch_bounds__(256) void k_feat(
    const float* __restrict__ mask_feat, const float* __restrict__ b_ctx,
    float* __restrict__ ws) {
  const int idx = blockIdx.x * 256 + threadIdx.x;  // 0..327679
  float* feat = ws + OFF_FEAT;
  if (idx < 65536) { feat[idx] = mask_feat[idx]; return; }
  const int r = idx - 65536;
  const int o = r >> 14, p = r & 16383;
  const int y = p >> 7, x = p & 127;
  float v = b_ctx[o] + ws[OFF_Y0 + o * 16384 + p];
  const unsigned offs[4] = {OFF_Y1, OFF_Y2, OFF_Y3, OFF_Y4};
  const int Ss[4] = {64, 32, 16, 8};
#pragma unroll
  for (int s = 0; s < 4; ++s) {
    const int S = Ss[s];
    const float sc = (float)S / 128.0f;
    const float fy = (y + 0.5f) * sc - 0.5f;
    const float fx = (x + 0.5f) * sc - 0.5f;
    const int iy = (int)floorf(fy), ix = (int)floorf(fx);
    const float ty = fy - (float)iy, tx = fx - (float)ix;
    const int y0 = iy < 0 ? 0 : iy;
    const int y1 = (iy + 1 > S - 1) ? S - 1 : iy + 1;
    const int x0 = ix < 0 ? 0 : ix;
    const int x1 = (ix + 1 > S - 1) ? S - 1 : ix + 1;
    const float* yb = ws + offs[s] + o * S * S;
    const float v00 = yb[y0 * S + x0], v01 = yb[y0 * S + x1];
    const float v10 = yb[y1 * S + x0], v11 = yb[y1 * S + x1];
    v += (1.f - ty) * ((1.f - tx) * v00 + tx * v01)
       + ty * ((1.f - tx) * v10 + tx * v11);
  }
  feat[(4 + o) * 16384 + p] = fmaxf(v, 0.f);
}

// ---------------- K3: x2 -> kin 24x24 (antialiased, padded 26x26) ----------
__global__ __launch_bounds__(256) void k_kin(
    const float* __restrict__ x2, float* __restrict__ ws) {
  const int idx = blockIdx.x * 256 + threadIdx.x;  // 256*676
  float* kin = ws + OFF_KIN;
  const int c = idx / 676, r = idx % 676;
  const int py = r / 26, px = r % 26;
  const int oy = py - 1, ox = px - 1;
  if (oy < 0 || oy >= 24 || ox < 0 || ox >= 24) { kin[idx] = 0.f; return; }
  float wy[4], wx[4];
  int iy0, ix0;
  {
    const float s = (oy + 0.5f) * (4.0f / 3.0f) - 0.5f;
    iy0 = (int)floorf(s) - 1;
    float sw = 0.f;
#pragma unroll
    for (int a = 0; a < 4; ++a) {
      const int i = iy0 + a;
      float w = fmaxf(1.0f - fabsf((float)i - s) * 0.75f, 0.f);
      if (i < 0 || i > 31) w = 0.f;
      wy[a] = w; sw += w;
    }
    const float inv = 1.0f / sw;
#pragma unroll
    for (int a = 0; a < 4; ++a) wy[a] *= inv;
  }
  {
    const float s = (ox + 0.5f) * (4.0f / 3.0f) - 0.5f;
    ix0 = (int)floorf(s) - 1;
    float sw = 0.f;
#pragma unroll
    for (int a = 0; a < 4; ++a) {
      const int i = ix0 + a;
      float w = fmaxf(1.0f - fabsf((float)i - s) * 0.75f, 0.f);
      if (i < 0 || i > 31) w = 0.f;
      wx[a] = w; sw += w;
    }
    const float inv = 1.0f / sw;
#pragma unroll
    for (int a = 0; a < 4; ++a) wx[a] *= inv;
  }
  float acc = 0.f;
#pragma unroll
  for (int a = 0; a < 4; ++a) {
    const int iy = min(max(iy0 + a, 0), 31);
    const float* row = x2 + c * 1024 + iy * 32;
#pragma unroll
    for (int bb = 0; bb < 4; ++bb) {
      const int ix = min(max(ix0 + bb, 0), 31);
      acc += wy[a] * wx[bb] * row[ix];
    }
  }
  kin[idx] = acc;
}

// ---------------- K4: 3x3 conv 256->249 over 24x24 -> kpT[n][249] ----------
__global__ __launch_bounds__(256) void k_kpconv(
    const float* __restrict__ w_lw, const float* __restrict__ b_lw,
    float* __restrict__ ws) {
  const int oc = blockIdx.x, tid = threadIdx.x;
  const float* kin = ws + OFF_KIN;
  float* kpT = ws + OFF_KPT;
  const float* __restrict__ wb = w_lw + oc * 2304;
  const float bias = b_lw[oc];
  float a0 = bias, a1 = bias, a2 = bias;
  const int p0 = tid, p1 = tid + 256;
  const bool has2 = tid < 64;
  const int p2 = has2 ? tid + 512 : tid;
  const int b0 = (p0 / 24) * 26 + (p0 % 24);
  const int b1 = (p1 / 24) * 26 + (p1 % 24);
  const int b2 = (p2 / 24) * 26 + (p2 % 24);
#pragma unroll 2
  for (int c = 0; c < 256; ++c) {
    const float* kb = kin + c * 676;
    const float* wc = wb + c * 9;
#pragma unroll
    for (int t = 0; t < 9; ++t) {
      const float w = wc[t];
      const int d = (t / 3) * 26 + (t % 3);
      a0 += w * kb[b0 + d];
      a1 += w * kb[b1 + d];
      a2 += w * kb[b2 + d];
    }
  }
  kpT[p0 * 249 + oc] = a0;
  kpT[p1 * 249 + oc] = a1;
  if (has2) kpT[p2 * 249 + oc] = a2;
}

// ---------------- K5: x0 -> 40x40 (antialiased, padded 42x42) --------------
__global__ __launch_bounds__(256) void k_x0r(
    const float* __restrict__ x0, float* __restrict__ ws) {
  const int idx = blockIdx.x * 256 + threadIdx.x;  // 256*1764
  float* xr = ws + OFF_X0R;
  const int c = idx / 1764, r = idx % 1764;
  const int py = r / 42, px = r % 42;
  const int oy = py - 1, ox = px - 1;
  if (oy < 0 || oy >= 40 || ox < 0 || ox >= 40) { xr[idx] = 0.f; return; }
  float wy[8], wx[8];
  int iy0, ix0;
  {
    const float s = (oy + 0.5f) * 3.2f - 0.5f;
    iy0 = (int)floorf(s) - 3;
    float sw = 0.f;
#pragma unroll
    for (int a = 0; a < 8; ++a) {
      const int i = iy0 + a;
      float w = fmaxf(1.0f - fabsf((float)i - s) * 0.3125f, 0.f);
      if (i < 0 || i > 127) w = 0.f;
      wy[a] = w; sw += w;
    }
    const float inv = 1.0f / sw;
#pragma unroll
    for (int a = 0; a < 8; ++a) wy[a] *= inv;
  }
  {
    const float s = (ox + 0.5f) * 3.2f - 0.5f;
    ix0 = (int)floorf(s) - 3;
    float sw = 0.f;
#pragma unroll
    for (int a = 0; a < 8; ++a) {
      const int i = ix0 + a;
      float w = fmaxf(1.0f - fabsf((float)i - s) * 0.3125f, 0.f);
      if (i < 0 || i > 127) w = 0.f;
      wx[a] = w; sw += w;
    }
    const float inv = 1.0f / sw;
#pragma unroll
    for (int a = 0; a < 8; ++a) wx[a] *= inv;
  }
  float acc = 0.f;
#pragma unroll
  for (int a = 0; a < 8; ++a) {
    const int iy = min(max(iy0 + a, 0), 127);
    const float* row = x0 + c * 16384 + iy * 128;
#pragma unroll
    for (int bb = 0; bb < 8; ++bb) {
      const int ix = min(max(ix0 + bb, 0), 127);
      acc += wy[a] * wx[bb] * row[ix];
    }
  }
  xr[idx] = acc;
}

// ---------------- K6: 3x3 conv 256->80 + sigmoid over 40x40 ----------------
__global__ __launch_bounds__(256) void k_cate(
    const float* __restrict__ w_cate, const float* __restrict__ b_cate,
    float* __restrict__ ws) {
  const int oc = blockIdx.x, tid = threadIdx.x;
  const int pb = blockIdx.y * 800;
  const float* xr = ws + OFF_X0R;
  float* cp = ws + OFF_CATE;
  const float* __restrict__ wb = w_cate + oc * 2304;
  const float bias = b_cate[oc];
  float a0 = bias, a1 = bias, a2 = bias, a3 = bias;
  const bool has3 = tid < 32;
  const int p0 = pb + tid, p1 = p0 + 256, p2 = p0 + 512;
  const int p3 = has3 ? p0 + 768 : p0;
  const int b0 = (p0 / 40) * 42 + (p0 % 40);
  const int b1 = (p1 / 40) * 42 + (p1 % 40);
  const int b2 = (p2 / 40) * 42 + (p2 % 40);
  const int b3 = (p3 / 40) * 42 + (p3 % 40);
#pragma unroll 2
  for (int c = 0; c < 256; ++c) {
    const float* xb = xr + c * 1764;
    const float* wc = wb + c * 9;
#pragma unroll
    for (int t = 0; t < 9; ++t) {
      const float w = wc[t];
      const int d = (t / 3) * 42 + (t % 3);
      a0 += w * xb[b0 + d];
      a1 += w * xb[b1 + d];
      a2 += w * xb[b2 + d];
      a3 += w * xb[b3 + d];
    }
  }
  cp[oc * 1600 + p0] = sigmoidf_(a0);
  cp[oc * 1600 + p1] = sigmoidf_(a1);
  cp[oc * 1600 + p2] = sigmoidf_(a2);
  if (has3) cp[oc * 1600 + p3] = sigmoidf_(a3);
}

// ---------------- K7: points_nms -> out tail -------------------------------
__global__ __launch_bounds__(256) void k_nms(
    const float* __restrict__ ws, float* __restrict__ out) {
  const int idx = blockIdx.x * 256 + threadIdx.x;  // 128000
  const float* cp = ws + OFF_CATE;
  const int r = idx % 1600, y = r / 40, x = r % 40;
  const float v = cp[idx];
  float m = v;
  if (y > 0 && x > 0) m = fmaxf(m, cp[idx - 41]);
  if (y > 0)          m = fmaxf(m, cp[idx - 40]);
  if (x > 0)          m = fmaxf(m, cp[idx - 1]);
  out[SEG_ELEMS + idx] = (m == v) ? v : 0.f;
}

// ---------------- K8: fused dynamic 3-layer MLP + sigmoid ------------------
#define POSB 8
__global__ __launch_bounds__(256) void k_dyn(
    const float* __restrict__ ws, float* __restrict__ out) {
  const int tid = threadIdx.x;
  const float* feat = ws + OFF_FEAT;
  const float* kpT = ws + OFF_KPT;
  const int pb = blockIdx.x * 1024 + tid * 4;
  float4 f[20];
#pragma unroll
  for (int e = 0; e < 20; ++e)
    f[e] = *reinterpret_cast<const float4*>(feat + e * 16384 + pb);
#pragma unroll 1
  for (int np = 0; np < POSB; ++np) {
    const int n = blockIdx.y * POSB + np;
    const float* __restrict__ w = kpT + n * 249;
    // layer 1: 20 -> 8, relu
    float h1x[8], h1y[8], h1z[8], h1w[8];
#pragma unroll
    for (int d = 0; d < 8; ++d) {
      float ax = w[160 + d], ay = ax, az = ax, aw = ax;
#pragma unroll
      for (int e = 0; e < 20; ++e) {
        const float wv = w[d * 20 + e];
        ax += wv * f[e].x; ay += wv * f[e].y;
        az += wv * f[e].z; aw += wv * f[e].w;
      }
      h1x[d] = fmaxf(ax, 0.f); h1y[d] = fmaxf(ay, 0.f);
      h1z[d] = fmaxf(az, 0.f); h1w[d] = fmaxf(aw, 0.f);
    }
    // layer 2: 8 -> 8, relu
    float h2x[8], h2y[8], h2z[8], h2w[8];
#pragma unroll
    for (int d = 0; d < 8; ++d) {
      float ax = w[232 + d], ay = ax, az = ax, aw = ax;
#pragma unroll
      for (int e = 0; e < 8; ++e) {
        const float wv = w[168 + d * 8 + e];
        ax += wv * h1x[e]; ay += wv * h1y[e];
        az += wv * h1z[e]; aw += wv * h1w[e];
      }
      h2x[d] = fmaxf(ax, 0.f); h2y[d] = fmaxf(ay, 0.f);
      h2z[d] = fmaxf(az, 0.f); h2w[d] = fmaxf(aw, 0.f);
    }
    // layer 3: 8 -> 1, sigmoid
    float mx = w[248], my = mx, mz = mx, mw = mx;
#pragma unroll
    for (int e = 0; e < 8; ++e) {
      const float wv = w[240 + e];
      mx += wv * h2x[e]; my += wv * h2y[e];
      mz += wv * h2z[e]; mw += wv * h2w[e];
    }
    float4 rr;
    rr.x = sigmoidf_(mx); rr.y = sigmoidf_(my);
    rr.z = sigmoidf_(mz); rr.w = sigmoidf_(mw);
    *reinterpret_cast<float4*>(out + (size_t)n * 16384 + pb) = rr;
  }
}

// ---------------------------------------------------------------------------
extern "C" void kernel_launch(void* const* d_in, const int* in_sizes, int n_in,
                              void* d_out, int out_size, void* d_ws, size_t ws_size,
                              hipStream_t stream) {
  const float* x0        = (const float*)d_in[0];
  const float* x1        = (const float*)d_in[1];
  const float* x2        = (const float*)d_in[2];
  const float* x3        = (const float*)d_in[3];
  const float* x4        = (const float*)d_in[4];
  const float* mask_feat = (const float*)d_in[5];
  const float* w_ctx     = (const float*)d_in[6];
  const float* b_ctx     = (const float*)d_in[7];
  const float* w_lw      = (const float*)d_in[8];
  const float* b_lw      = (const float*)d_in[9];
  const float* w_cate    = (const float*)d_in[10];
  const float* b_cate    = (const float*)d_in[11];
  float* out = (float*)d_out;
  float* ws  = (float*)d_ws;

  hipLaunchKernelGGL(k_gemm_ys, dim3(86), dim3(256), 0, stream,
                     x0, x1, x2, x3, x4, w_ctx, ws);
  hipLaunchKernelGGL(k_feat, dim3(1280), dim3(256), 0, stream,
                     mask_feat, b_ctx, ws);
  hipLaunchKernelGGL(k_kin, dim3(676), dim3(256), 0, stream, x2, ws);
  hipLaunchKernelGGL(k_kpconv, dim3(249), dim3(256), 0, stream,
                     w_lw, b_lw, ws);
  hipLaunchKernelGGL(k_x0r, dim3(1764), dim3(256), 0, stream, x0, ws);
  hipLaunchKernelGGL(k_cate, dim3(80, 2), dim3(256), 0, stream,
                     w_cate, b_cate, ws);
  hipLaunchKernelGGL(k_nms, dim3(500), dim3(256), 0, stream, ws, out);
  hipLaunchKernelGGL(k_dyn, dim3(16, 72), dim3(256), 0, stream, ws, out);
}

// Round 2
// 300.491 us; speedup vs baseline: 1.6150x; 1.6150x over previous
//
#include <hip/hip_runtime.h>

// ---------------------------------------------------------------------------
// AggMaskStarHead: SOLO-style dynamic mask head, fp32 throughout.
//
//  K1 k_gemm_ys : 16x256 GEMM per source at native res, 4-way channel split
//                 within block (1 wave = 1 slice), LDS reduce
//  K2 k_feat    : feat[20][16384] = [mask_feat(4); relu(b + y0 + sum bilin(ys))]
//  K3 k_kin     : x2 (32x32) -> kin (24x24) antialiased, padded 26x26
//  K4 k_kpconv  : 3x3 conv 256->249 over 24x24, 8-way channel split -> partials
//  K4b k_kpred  : sum 8 partials + bias -> kpT[576][249]
//  K5 k_x0r     : x0 (128x128) -> 40x40 antialiased, padded 42x42
//  K6 k_cate    : 3x3 conv 256->80, 8-way channel split -> partials
//  K6b k_catered: sum 8 partials + bias + sigmoid -> cate_pre
//  K7 k_nms     : points_nms -> out tail
//  K8 k_dyn     : fused 3-layer dynamic MLP + sigmoid -> out head
// ---------------------------------------------------------------------------

// workspace float offsets
#define OFF_Y0   0u           // 16*16384
#define OFF_Y1   262144u      // 16*4096
#define OFF_Y2   327680u      // 16*1024
#define OFF_Y3   344064u      // 16*256
#define OFF_Y4   348160u      // 16*64
#define OFF_FEAT 349184u      // 20*16384
#define OFF_KIN  676864u      // 256*676  (26x26 zero-padded)
#define OFF_KPT  849920u      // 576*249
#define OFF_X0R  993344u      // 256*1764 (42x42 zero-padded)
#define OFF_CATE 1444928u     // 80*1600
#define OFF_KPP  1572928u     // 8*249*576 kpconv partials
#define OFF_CPP  2720320u     // 8*80*1600 cate partials
// total 3744320 floats ~= 15 MB

#define SEG_ELEMS 9437184     // 576*128*128

__device__ __forceinline__ float sigmoidf_(float x) {
  return 1.0f / (1.0f + __expf(-x));
}

// ---------------- K1: per-source 16x256 GEMMs (4-way channel split) --------
__global__ __launch_bounds__(256) void k_gemm_ys(
    const float* __restrict__ x0, const float* __restrict__ x1,
    const float* __restrict__ x2, const float* __restrict__ x3,
    const float* __restrict__ x4, const float* __restrict__ w_ctx,
    float* __restrict__ ws) {
  __shared__ float wl[4096];   // [c][o]
  __shared__ float red[4096];  // [slice][o][px]
  const int b = blockIdx.x, tid = threadIdx.x;
  int s, Q, qb;
  const float* xs;
  float* ys;
  if (b < 256)      { s = 0; xs = x0; ys = ws + OFF_Y0; Q = 16384; qb = b * 64; }
  else if (b < 320) { s = 1; xs = x1; ys = ws + OFF_Y1; Q = 4096;  qb = (b - 256) * 64; }
  else if (b < 336) { s = 2; xs = x2; ys = ws + OFF_Y2; Q = 1024;  qb = (b - 320) * 64; }
  else if (b < 340) { s = 3; xs = x3; ys = ws + OFF_Y3; Q = 256;   qb = (b - 336) * 64; }
  else              { s = 4; xs = x4; ys = ws + OFF_Y4; Q = 64;    qb = 0; }
  for (int i = tid; i < 4096; i += 256) {
    const int c = i >> 4, o = i & 15;
    wl[i] = w_ctx[o * 1280 + s * 256 + c];
  }
  __syncthreads();
  const int slice = tid >> 6, px = tid & 63;
  const int q = qb + px;
  float acc[16];
#pragma unroll
  for (int o = 0; o < 16; ++o) acc[o] = 0.f;
  const int c0 = slice * 64;
  for (int c = c0; c < c0 + 64; ++c) {
    const float v = xs[c * Q + q];
    const float* wc = &wl[c * 16];   // wave-uniform -> LDS broadcast
#pragma unroll
    for (int o = 0; o < 16; ++o) acc[o] += wc[o] * v;
  }
#pragma unroll
  for (int o = 0; o < 16; ++o) red[slice * 1024 + o * 64 + px] = acc[o];
  __syncthreads();
  const int og = tid >> 6;  // 4 outputs per thread
#pragma unroll
  for (int j = 0; j < 4; ++j) {
    const int o = og * 4 + j;
    const float v = red[o * 64 + px] + red[1024 + o * 64 + px] +
                    red[2048 + o * 64 + px] + red[3072 + o * 64 + px];
    ys[o * Q + qb + px] = v;
  }
}

// ---------------- K2: build feat = [mask_feat; relu(ctx)] ------------------
__global__ __launch_bounds__(256) void k_feat(
    const float* __restrict__ mask_feat, const float* __restrict__ b_ctx,
    float* __restrict__ ws) {
  const int idx = blockIdx.x * 256 + threadIdx.x;  // 0..327679
  float* feat = ws + OFF_FEAT;
  if (idx < 65536) { feat[idx] = mask_feat[idx]; return; }
  const int r = idx - 65536;
  const int o = r >> 14, p = r & 16383;
  const int y = p >> 7, x = p & 127;
  float v = b_ctx[o] + ws[OFF_Y0 + o * 16384 + p];
  const unsigned offs[4] = {OFF_Y1, OFF_Y2, OFF_Y3, OFF_Y4};
  const int Ss[4] = {64, 32, 16, 8};
#pragma unroll
  for (int s = 0; s < 4; ++s) {
    const int S = Ss[s];
    const float sc = (float)S / 128.0f;
    const float fy = (y + 0.5f) * sc - 0.5f;
    const float fx = (x + 0.5f) * sc - 0.5f;
    const int iy = (int)floorf(fy), ix = (int)floorf(fx);
    const float ty = fy - (float)iy, tx = fx - (float)ix;
    const int y0 = iy < 0 ? 0 : iy;
    const int y1 = (iy + 1 > S - 1) ? S - 1 : iy + 1;
    const int x0 = ix < 0 ? 0 : ix;
    const int x1 = (ix + 1 > S - 1) ? S - 1 : ix + 1;
    const float* yb = ws + offs[s] + o * S * S;
    const float v00 = yb[y0 * S + x0], v01 = yb[y0 * S + x1];
    const float v10 = yb[y1 * S + x0], v11 = yb[y1 * S + x1];
    v += (1.f - ty) * ((1.f - tx) * v00 + tx * v01)
       + ty * ((1.f - tx) * v10 + tx * v11);
  }
  feat[(4 + o) * 16384 + p] = fmaxf(v, 0.f);
}

// ---------------- K3: x2 -> kin 24x24 (antialiased, padded 26x26) ----------
__global__ __launch_bounds__(256) void k_kin(
    const float* __restrict__ x2, float* __restrict__ ws) {
  const int idx = blockIdx.x * 256 + threadIdx.x;  // 256*676
  float* kin = ws + OFF_KIN;
  const int c = idx / 676, r = idx % 676;
  const int py = r / 26, px = r % 26;
  const int oy = py - 1, ox = px - 1;
  if (oy < 0 || oy >= 24 || ox < 0 || ox >= 24) { kin[idx] = 0.f; return; }
  float wy[4], wx[4];
  int iy0, ix0;
  {
    const float s = (oy + 0.5f) * (4.0f / 3.0f) - 0.5f;
    iy0 = (int)floorf(s) - 1;
    float sw = 0.f;
#pragma unroll
    for (int a = 0; a < 4; ++a) {
      const int i = iy0 + a;
      float w = fmaxf(1.0f - fabsf((float)i - s) * 0.75f, 0.f);
      if (i < 0 || i > 31) w = 0.f;
      wy[a] = w; sw += w;
    }
    const float inv = 1.0f / sw;
#pragma unroll
    for (int a = 0; a < 4; ++a) wy[a] *= inv;
  }
  {
    const float s = (ox + 0.5f) * (4.0f / 3.0f) - 0.5f;
    ix0 = (int)floorf(s) - 1;
    float sw = 0.f;
#pragma unroll
    for (int a = 0; a < 4; ++a) {
      const int i = ix0 + a;
      float w = fmaxf(1.0f - fabsf((float)i - s) * 0.75f, 0.f);
      if (i < 0 || i > 31) w = 0.f;
      wx[a] = w; sw += w;
    }
    const float inv = 1.0f / sw;
#pragma unroll
    for (int a = 0; a < 4; ++a) wx[a] *= inv;
  }
  float acc = 0.f;
#pragma unroll
  for (int a = 0; a < 4; ++a) {
    const int iy = min(max(iy0 + a, 0), 31);
    const float* row = x2 + c * 1024 + iy * 32;
#pragma unroll
    for (int bb = 0; bb < 4; ++bb) {
      const int ix = min(max(ix0 + bb, 0), 31);
      acc += wy[a] * wx[bb] * row[ix];
    }
  }
  kin[idx] = acc;
}

// ---------------- K4: 3x3 conv 256->249, 8-way channel split ---------------
__global__ __launch_bounds__(256) void k_kpconv(
    const float* __restrict__ w_lw, float* __restrict__ ws) {
  const int oc = blockIdx.x, sl = blockIdx.y, tid = threadIdx.x;
  const float* kin = ws + OFF_KIN;
  float* pp = ws + OFF_KPP + ((unsigned)(sl * 249 + oc)) * 576u;
  const float* __restrict__ wb = w_lw + oc * 2304 + sl * 32 * 9;
  float a0 = 0.f, a1 = 0.f, a2 = 0.f;
  const int p0 = tid, p1 = tid + 256;
  const bool has2 = tid < 64;
  const int p2 = has2 ? tid + 512 : tid;
  const int b0 = (p0 / 24) * 26 + (p0 % 24);
  const int b1 = (p1 / 24) * 26 + (p1 % 24);
  const int b2 = (p2 / 24) * 26 + (p2 % 24);
  const float* kb = kin + sl * 32 * 676;
#pragma unroll 2
  for (int c = 0; c < 32; ++c) {
    const float* kc = kb + c * 676;
    const float* wc = wb + c * 9;
#pragma unroll
    for (int t = 0; t < 9; ++t) {
      const float w = wc[t];
      const int d = (t / 3) * 26 + (t % 3);
      a0 += w * kc[b0 + d];
      a1 += w * kc[b1 + d];
      a2 += w * kc[b2 + d];
    }
  }
  pp[p0] = a0;
  pp[p1] = a1;
  if (has2) pp[p2] = a2;
}

// ---------------- K4b: reduce kpconv partials -> kpT[576][249] -------------
__global__ __launch_bounds__(256) void k_kpred(
    const float* __restrict__ b_lw, float* __restrict__ ws) {
  const int idx = blockIdx.x * 256 + threadIdx.x;
  if (idx >= 249 * 576) return;
  const int oc = idx / 576, p = idx % 576;
  const float* pp = ws + OFF_KPP;
  float s = b_lw[oc];
#pragma unroll
  for (int sl = 0; sl < 8; ++sl) s += pp[((unsigned)(sl * 249 + oc)) * 576u + p];
  ws[OFF_KPT + (unsigned)p * 249u + oc] = s;
}

// ---------------- K5: x0 -> 40x40 (antialiased, padded 42x42) --------------
__global__ __launch_bounds__(256) void k_x0r(
    const float* __restrict__ x0, float* __restrict__ ws) {
  const int idx = blockIdx.x * 256 + threadIdx.x;  // 256*1764
  float* xr = ws + OFF_X0R;
  const int c = idx / 1764, r = idx % 1764;
  const int py = r / 42, px = r % 42;
  const int oy = py - 1, ox = px - 1;
  if (oy < 0 || oy >= 40 || ox < 0 || ox >= 40) { xr[idx] = 0.f; return; }
  float wy[8], wx[8];
  int iy0, ix0;
  {
    const float s = (oy + 0.5f) * 3.2f - 0.5f;
    iy0 = (int)floorf(s) - 3;
    float sw = 0.f;
#pragma unroll
    for (int a = 0; a < 8; ++a) {
      const int i = iy0 + a;
      float w = fmaxf(1.0f - fabsf((float)i - s) * 0.3125f, 0.f);
      if (i < 0 || i > 127) w = 0.f;
      wy[a] = w; sw += w;
    }
    const float inv = 1.0f / sw;
#pragma unroll
    for (int a = 0; a < 8; ++a) wy[a] *= inv;
  }
  {
    const float s = (ox + 0.5f) * 3.2f - 0.5f;
    ix0 = (int)floorf(s) - 3;
    float sw = 0.f;
#pragma unroll
    for (int a = 0; a < 8; ++a) {
      const int i = ix0 + a;
      float w = fmaxf(1.0f - fabsf((float)i - s) * 0.3125f, 0.f);
      if (i < 0 || i > 127) w = 0.f;
      wx[a] = w; sw += w;
    }
    const float inv = 1.0f / sw;
#pragma unroll
    for (int a = 0; a < 8; ++a) wx[a] *= inv;
  }
  float acc = 0.f;
#pragma unroll
  for (int a = 0; a < 8; ++a) {
    const int iy = min(max(iy0 + a, 0), 127);
    const float* row = x0 + c * 16384 + iy * 128;
#pragma unroll
    for (int bb = 0; bb < 8; ++bb) {
      const int ix = min(max(ix0 + bb, 0), 127);
      acc += wy[a] * wx[bb] * row[ix];
    }
  }
  xr[idx] = acc;
}

// ---------------- K6: 3x3 conv 256->80, 8-way channel split ----------------
__global__ __launch_bounds__(256) void k_cate(
    const float* __restrict__ w_cate, float* __restrict__ ws) {
  const int oc = blockIdx.x, tid = threadIdx.x;
  const int pb = blockIdx.y * 800;
  const int sl = blockIdx.z;
  const float* xr = ws + OFF_X0R;
  float* pp = ws + OFF_CPP + ((unsigned)(sl * 80 + oc)) * 1600u;
  const float* __restrict__ wb = w_cate + oc * 2304 + sl * 32 * 9;
  float a0 = 0.f, a1 = 0.f, a2 = 0.f, a3 = 0.f;
  const bool has3 = tid < 32;
  const int p0 = pb + tid, p1 = p0 + 256, p2 = p0 + 512;
  const int p3 = has3 ? p0 + 768 : p0;
  const int b0 = (p0 / 40) * 42 + (p0 % 40);
  const int b1 = (p1 / 40) * 42 + (p1 % 40);
  const int b2 = (p2 / 40) * 42 + (p2 % 40);
  const int b3 = (p3 / 40) * 42 + (p3 % 40);
  const float* xb0 = xr + sl * 32 * 1764;
#pragma unroll 2
  for (int c = 0; c < 32; ++c) {
    const float* xb = xb0 + c * 1764;
    const float* wc = wb + c * 9;
#pragma unroll
    for (int t = 0; t < 9; ++t) {
      const float w = wc[t];
      const int d = (t / 3) * 42 + (t % 3);
      a0 += w * xb[b0 + d];
      a1 += w * xb[b1 + d];
      a2 += w * xb[b2 + d];
      a3 += w * xb[b3 + d];
    }
  }
  pp[p0] = a0;
  pp[p1] = a1;
  pp[p2] = a2;
  if (has3) pp[p3] = a3;
}

// ---------------- K6b: reduce cate partials + bias + sigmoid ---------------
__global__ __launch_bounds__(256) void k_catered(
    const float* __restrict__ b_cate, float* __restrict__ ws) {
  const int idx = blockIdx.x * 256 + threadIdx.x;  // 128000
  const int oc = idx / 1600;
  const float* pp = ws + OFF_CPP;
  float s = b_cate[oc];
#pragma unroll
  for (int sl = 0; sl < 8; ++sl) s += pp[(unsigned)sl * 128000u + idx];
  ws[OFF_CATE + idx] = sigmoidf_(s);
}

// ---------------- K7: points_nms -> out tail -------------------------------
__global__ __launch_bounds__(256) void k_nms(
    const float* __restrict__ ws, float* __restrict__ out) {
  const int idx = blockIdx.x * 256 + threadIdx.x;  // 128000
  const float* cp = ws + OFF_CATE;
  const int r = idx % 1600, y = r / 40, x = r % 40;
  const float v = cp[idx];
  float m = v;
  if (y > 0 && x > 0) m = fmaxf(m, cp[idx - 41]);
  if (y > 0)          m = fmaxf(m, cp[idx - 40]);
  if (x > 0)          m = fmaxf(m, cp[idx - 1]);
  out[SEG_ELEMS + idx] = (m == v) ? v : 0.f;
}

// ---------------- K8: fused dynamic 3-layer MLP + sigmoid ------------------
#define POSB 8
__global__ __launch_bounds__(256) void k_dyn(
    const float* __restrict__ ws, float* __restrict__ out) {
  const int tid = threadIdx.x;
  const float* feat = ws + OFF_FEAT;
  const float* kpT = ws + OFF_KPT;
  const int pb = blockIdx.x * 1024 + tid * 4;
  float4 f[20];
#pragma unroll
  for (int e = 0; e < 20; ++e)
    f[e] = *reinterpret_cast<const float4*>(feat + e * 16384 + pb);
#pragma unroll 1
  for (int np = 0; np < POSB; ++np) {
    const int n = blockIdx.y * POSB + np;
    const float* __restrict__ w = kpT + n * 249;
    float h1x[8], h1y[8], h1z[8], h1w[8];
#pragma unroll
    for (int d = 0; d < 8; ++d) {
      float ax = w[160 + d], ay = ax, az = ax, aw = ax;
#pragma unroll
      for (int e = 0; e < 20; ++e) {
        const float wv = w[d * 20 + e];
        ax += wv * f[e].x; ay += wv * f[e].y;
        az += wv * f[e].z; aw += wv * f[e].w;
      }
      h1x[d] = fmaxf(ax, 0.f); h1y[d] = fmaxf(ay, 0.f);
      h1z[d] = fmaxf(az, 0.f); h1w[d] = fmaxf(aw, 0.f);
    }
    float h2x[8], h2y[8], h2z[8], h2w[8];
#pragma unroll
    for (int d = 0; d < 8; ++d) {
      float ax = w[232 + d], ay = ax, az = ax, aw = ax;
#pragma unroll
      for (int e = 0; e < 8; ++e) {
        const float wv = w[168 + d * 8 + e];
        ax += wv * h1x[e]; ay += wv * h1y[e];
        az += wv * h1z[e]; aw += wv * h1w[e];
      }
      h2x[d] = fmaxf(ax, 0.f); h2y[d] = fmaxf(ay, 0.f);
      h2z[d] = fmaxf(az, 0.f); h2w[d] = fmaxf(aw, 0.f);
    }
    float mx = w[248], my = mx, mz = mx, mw = mx;
#pragma unroll
    for (int e = 0; e < 8; ++e) {
      const float wv = w[240 + e];
      mx += wv * h2x[e]; my += wv * h2y[e];
      mz += wv * h2z[e]; mw += wv * h2w[e];
    }
    float4 rr;
    rr.x = sigmoidf_(mx); rr.y = sigmoidf_(my);
    rr.z = sigmoidf_(mz); rr.w = sigmoidf_(mw);
    *reinterpret_cast<float4*>(out + (size_t)n * 16384 + pb) = rr;
  }
}

// ---------------------------------------------------------------------------
extern "C" void kernel_launch(void* const* d_in, const int* in_sizes, int n_in,
                              void* d_out, int out_size, void* d_ws, size_t ws_size,
                              hipStream_t stream) {
  const float* x0        = (const float*)d_in[0];
  const float* x1        = (const float*)d_in[1];
  const float* x2        = (const float*)d_in[2];
  const float* x3        = (const float*)d_in[3];
  const float* x4        = (const float*)d_in[4];
  const float* mask_feat = (const float*)d_in[5];
  const float* w_ctx     = (const float*)d_in[6];
  const float* b_ctx     = (const float*)d_in[7];
  const float* w_lw      = (const float*)d_in[8];
  const float* b_lw      = (const float*)d_in[9];
  const float* w_cate    = (const float*)d_in[10];
  const float* b_cate    = (const float*)d_in[11];
  float* out = (float*)d_out;
  float* ws  = (float*)d_ws;

  hipLaunchKernelGGL(k_gemm_ys, dim3(341), dim3(256), 0, stream,
                     x0, x1, x2, x3, x4, w_ctx, ws);
  hipLaunchKernelGGL(k_feat, dim3(1280), dim3(256), 0, stream,
                     mask_feat, b_ctx, ws);
  hipLaunchKernelGGL(k_kin, dim3(676), dim3(256), 0, stream, x2, ws);
  hipLaunchKernelGGL(k_kpconv, dim3(249, 8), dim3(256), 0, stream, w_lw, ws);
  hipLaunchKernelGGL(k_kpred, dim3(561), dim3(256), 0, stream, b_lw, ws);
  hipLaunchKernelGGL(k_x0r, dim3(1764), dim3(256), 0, stream, x0, ws);
  hipLaunchKernelGGL(k_cate, dim3(80, 2, 8), dim3(256), 0, stream, w_cate, ws);
  hipLaunchKernelGGL(k_catered, dim3(500), dim3(256), 0, stream, b_cate, ws);
  hipLaunchKernelGGL(k_nms, dim3(500), dim3(256), 0, stream, ws, out);
  hipLaunchKernelGGL(k_dyn, dim3(16, 72), dim3(256), 0, stream, ws, out);
}

// Round 3
// 286.825 us; speedup vs baseline: 1.6920x; 1.0476x over previous
//
#include <hip/hip_runtime.h>

// ---------------------------------------------------------------------------
// AggMaskStarHead: SOLO-style dynamic mask head, fp32 throughout.
//
//  K1 k_gemm_ys : 16x256 GEMM per source at native res, 4-way channel split
//                 within block (1 wave = 1 slice), LDS reduce
//  K2 k_feat    : feat[20][16384] = [mask_feat(4); relu(b + y0 + sum bilin(ys))]
//  K3 k_kin     : x2 (32x32) -> kin (24x24) antialiased, padded 26x26
//  K4 k_kpconv  : 3x3 conv 256->249 over 24x24, 8-way channel split -> partials
//  K4b k_kpred  : sum 8 partials + bias -> kpT[576][249]
//  K5 k_x0r     : x0 (128x128) -> 40x40 antialiased, padded 42x42
//  K6 k_cate    : 3x3 conv 256->80, 8-way channel split -> partials
//  K6b k_catered: sum 8 partials + bias + sigmoid -> cate_pre
//  K7 k_nms     : points_nms -> out tail
//  K8 k_dyn     : fused 3-layer dynamic MLP + sigmoid -> out head
//                 (launch_bounds(256,2): VGPR cap 256 so f[20] float4 stays
//                  register-resident across the position loop — R2's VGPR=76
//                  showed the loads were sunk into the loop -> L2-latency-bound)
// ---------------------------------------------------------------------------

// workspace float offsets
#define OFF_Y0   0u           // 16*16384
#define OFF_Y1   262144u      // 16*4096
#define OFF_Y2   327680u      // 16*1024
#define OFF_Y3   344064u      // 16*256
#define OFF_Y4   348160u      // 16*64
#define OFF_FEAT 349184u      // 20*16384
#define OFF_KIN  676864u      // 256*676  (26x26 zero-padded)
#define OFF_KPT  849920u      // 576*249
#define OFF_X0R  993344u      // 256*1764 (42x42 zero-padded)
#define OFF_CATE 1444928u     // 80*1600
#define OFF_KPP  1572928u     // 8*249*576 kpconv partials
#define OFF_CPP  2720320u     // 8*80*1600 cate partials
// total 3744320 floats ~= 15 MB

#define SEG_ELEMS 9437184     // 576*128*128

__device__ __forceinline__ float sigmoidf_(float x) {
  return 1.0f / (1.0f + __expf(-x));
}

// ---------------- K1: per-source 16x256 GEMMs (4-way channel split) --------
__global__ __launch_bounds__(256) void k_gemm_ys(
    const float* __restrict__ x0, const float* __restrict__ x1,
    const float* __restrict__ x2, const float* __restrict__ x3,
    const float* __restrict__ x4, const float* __restrict__ w_ctx,
    float* __restrict__ ws) {
  __shared__ float wl[4096];   // [c][o]
  __shared__ float red[4096];  // [slice][o][px]
  const int b = blockIdx.x, tid = threadIdx.x;
  int s, Q, qb;
  const float* xs;
  float* ys;
  if (b < 256)      { s = 0; xs = x0; ys = ws + OFF_Y0; Q = 16384; qb = b * 64; }
  else if (b < 320) { s = 1; xs = x1; ys = ws + OFF_Y1; Q = 4096;  qb = (b - 256) * 64; }
  else if (b < 336) { s = 2; xs = x2; ys = ws + OFF_Y2; Q = 1024;  qb = (b - 320) * 64; }
  else if (b < 340) { s = 3; xs = x3; ys = ws + OFF_Y3; Q = 256;   qb = (b - 336) * 64; }
  else              { s = 4; xs = x4; ys = ws + OFF_Y4; Q = 64;    qb = 0; }
  for (int i = tid; i < 4096; i += 256) {
    const int c = i >> 4, o = i & 15;
    wl[i] = w_ctx[o * 1280 + s * 256 + c];
  }
  __syncthreads();
  const int slice = tid >> 6, px = tid & 63;
  const int q = qb + px;
  float acc[16];
#pragma unroll
  for (int o = 0; o < 16; ++o) acc[o] = 0.f;
  const int c0 = slice * 64;
  for (int c = c0; c < c0 + 64; ++c) {
    const float v = xs[c * Q + q];
    const float* wc = &wl[c * 16];   // wave-uniform -> LDS broadcast
#pragma unroll
    for (int o = 0; o < 16; ++o) acc[o] += wc[o] * v;
  }
#pragma unroll
  for (int o = 0; o < 16; ++o) red[slice * 1024 + o * 64 + px] = acc[o];
  __syncthreads();
  const int og = tid >> 6;  // 4 outputs per thread
#pragma unroll
  for (int j = 0; j < 4; ++j) {
    const int o = og * 4 + j;
    const float v = red[o * 64 + px] + red[1024 + o * 64 + px] +
                    red[2048 + o * 64 + px] + red[3072 + o * 64 + px];
    ys[o * Q + qb + px] = v;
  }
}

// ---------------- K2: build feat = [mask_feat; relu(ctx)] ------------------
__global__ __launch_bounds__(256) void k_feat(
    const float* __restrict__ mask_feat, const float* __restrict__ b_ctx,
    float* __restrict__ ws) {
  const int idx = blockIdx.x * 256 + threadIdx.x;  // 0..327679
  float* feat = ws + OFF_FEAT;
  if (idx < 65536) { feat[idx] = mask_feat[idx]; return; }
  const int r = idx - 65536;
  const int o = r >> 14, p = r & 16383;
  const int y = p >> 7, x = p & 127;
  float v = b_ctx[o] + ws[OFF_Y0 + o * 16384 + p];
  const unsigned offs[4] = {OFF_Y1, OFF_Y2, OFF_Y3, OFF_Y4};
  const int Ss[4] = {64, 32, 16, 8};
#pragma unroll
  for (int s = 0; s < 4; ++s) {
    const int S = Ss[s];
    const float sc = (float)S / 128.0f;
    const float fy = (y + 0.5f) * sc - 0.5f;
    const float fx = (x + 0.5f) * sc - 0.5f;
    const int iy = (int)floorf(fy), ix = (int)floorf(fx);
    const float ty = fy - (float)iy, tx = fx - (float)ix;
    const int y0 = iy < 0 ? 0 : iy;
    const int y1 = (iy + 1 > S - 1) ? S - 1 : iy + 1;
    const int x0 = ix < 0 ? 0 : ix;
    const int x1 = (ix + 1 > S - 1) ? S - 1 : ix + 1;
    const float* yb = ws + offs[s] + o * S * S;
    const float v00 = yb[y0 * S + x0], v01 = yb[y0 * S + x1];
    const float v10 = yb[y1 * S + x0], v11 = yb[y1 * S + x1];
    v += (1.f - ty) * ((1.f - tx) * v00 + tx * v01)
       + ty * ((1.f - tx) * v10 + tx * v11);
  }
  feat[(4 + o) * 16384 + p] = fmaxf(v, 0.f);
}

// ---------------- K3: x2 -> kin 24x24 (antialiased, padded 26x26) ----------
__global__ __launch_bounds__(256) void k_kin(
    const float* __restrict__ x2, float* __restrict__ ws) {
  const int idx = blockIdx.x * 256 + threadIdx.x;  // 256*676
  float* kin = ws + OFF_KIN;
  const int c = idx / 676, r = idx % 676;
  const int py = r / 26, px = r % 26;
  const int oy = py - 1, ox = px - 1;
  if (oy < 0 || oy >= 24 || ox < 0 || ox >= 24) { kin[idx] = 0.f; return; }
  float wy[4], wx[4];
  int iy0, ix0;
  {
    const float s = (oy + 0.5f) * (4.0f / 3.0f) - 0.5f;
    iy0 = (int)floorf(s) - 1;
    float sw = 0.f;
#pragma unroll
    for (int a = 0; a < 4; ++a) {
      const int i = iy0 + a;
      float w = fmaxf(1.0f - fabsf((float)i - s) * 0.75f, 0.f);
      if (i < 0 || i > 31) w = 0.f;
      wy[a] = w; sw += w;
    }
    const float inv = 1.0f / sw;
#pragma unroll
    for (int a = 0; a < 4; ++a) wy[a] *= inv;
  }
  {
    const float s = (ox + 0.5f) * (4.0f / 3.0f) - 0.5f;
    ix0 = (int)floorf(s) - 1;
    float sw = 0.f;
#pragma unroll
    for (int a = 0; a < 4; ++a) {
      const int i = ix0 + a;
      float w = fmaxf(1.0f - fabsf((float)i - s) * 0.75f, 0.f);
      if (i < 0 || i > 31) w = 0.f;
      wx[a] = w; sw += w;
    }
    const float inv = 1.0f / sw;
#pragma unroll
    for (int a = 0; a < 4; ++a) wx[a] *= inv;
  }
  float acc = 0.f;
#pragma unroll
  for (int a = 0; a < 4; ++a) {
    const int iy = min(max(iy0 + a, 0), 31);
    const float* row = x2 + c * 1024 + iy * 32;
#pragma unroll
    for (int bb = 0; bb < 4; ++bb) {
      const int ix = min(max(ix0 + bb, 0), 31);
      acc += wy[a] * wx[bb] * row[ix];
    }
  }
  kin[idx] = acc;
}

// ---------------- K4: 3x3 conv 256->249, 8-way channel split ---------------
__global__ __launch_bounds__(256) void k_kpconv(
    const float* __restrict__ w_lw, float* __restrict__ ws) {
  const int oc = blockIdx.x, sl = blockIdx.y, tid = threadIdx.x;
  const float* kin = ws + OFF_KIN;
  float* pp = ws + OFF_KPP + ((unsigned)(sl * 249 + oc)) * 576u;
  const float* __restrict__ wb = w_lw + oc * 2304 + sl * 32 * 9;
  float a0 = 0.f, a1 = 0.f, a2 = 0.f;
  const int p0 = tid, p1 = tid + 256;
  const bool has2 = tid < 64;
  const int p2 = has2 ? tid + 512 : tid;
  const int b0 = (p0 / 24) * 26 + (p0 % 24);
  const int b1 = (p1 / 24) * 26 + (p1 % 24);
  const int b2 = (p2 / 24) * 26 + (p2 % 24);
  const float* kb = kin + sl * 32 * 676;
#pragma unroll 2
  for (int c = 0; c < 32; ++c) {
    const float* kc = kb + c * 676;
    const float* wc = wb + c * 9;
#pragma unroll
    for (int t = 0; t < 9; ++t) {
      const float w = wc[t];
      const int d = (t / 3) * 26 + (t % 3);
      a0 += w * kc[b0 + d];
      a1 += w * kc[b1 + d];
      a2 += w * kc[b2 + d];
    }
  }
  pp[p0] = a0;
  pp[p1] = a1;
  if (has2) pp[p2] = a2;
}

// ---------------- K4b: reduce kpconv partials -> kpT[576][249] -------------
__global__ __launch_bounds__(256) void k_kpred(
    const float* __restrict__ b_lw, float* __restrict__ ws) {
  const int idx = blockIdx.x * 256 + threadIdx.x;
  if (idx >= 249 * 576) return;
  const int oc = idx / 576, p = idx % 576;
  const float* pp = ws + OFF_KPP;
  float s = b_lw[oc];
#pragma unroll
  for (int sl = 0; sl < 8; ++sl) s += pp[((unsigned)(sl * 249 + oc)) * 576u + p];
  ws[OFF_KPT + (unsigned)p * 249u + oc] = s;
}

// ---------------- K5: x0 -> 40x40 (antialiased, padded 42x42) --------------
__global__ __launch_bounds__(256) void k_x0r(
    const float* __restrict__ x0, float* __restrict__ ws) {
  const int idx = blockIdx.x * 256 + threadIdx.x;  // 256*1764
  float* xr = ws + OFF_X0R;
  const int c = idx / 1764, r = idx % 1764;
  const int py = r / 42, px = r % 42;
  const int oy = py - 1, ox = px - 1;
  if (oy < 0 || oy >= 40 || ox < 0 || ox >= 40) { xr[idx] = 0.f; return; }
  float wy[8], wx[8];
  int iy0, ix0;
  {
    const float s = (oy + 0.5f) * 3.2f - 0.5f;
    iy0 = (int)floorf(s) - 3;
    float sw = 0.f;
#pragma unroll
    for (int a = 0; a < 8; ++a) {
      const int i = iy0 + a;
      float w = fmaxf(1.0f - fabsf((float)i - s) * 0.3125f, 0.f);
      if (i < 0 || i > 127) w = 0.f;
      wy[a] = w; sw += w;
    }
    const float inv = 1.0f / sw;
#pragma unroll
    for (int a = 0; a < 8; ++a) wy[a] *= inv;
  }
  {
    const float s = (ox + 0.5f) * 3.2f - 0.5f;
    ix0 = (int)floorf(s) - 3;
    float sw = 0.f;
#pragma unroll
    for (int a = 0; a < 8; ++a) {
      const int i = ix0 + a;
      float w = fmaxf(1.0f - fabsf((float)i - s) * 0.3125f, 0.f);
      if (i < 0 || i > 127) w = 0.f;
      wx[a] = w; sw += w;
    }
    const float inv = 1.0f / sw;
#pragma unroll
    for (int a = 0; a < 8; ++a) wx[a] *= inv;
  }
  float acc = 0.f;
#pragma unroll
  for (int a = 0; a < 8; ++a) {
    const int iy = min(max(iy0 + a, 0), 127);
    const float* row = x0 + c * 16384 + iy * 128;
#pragma unroll
    for (int bb = 0; bb < 8; ++bb) {
      const int ix = min(max(ix0 + bb, 0), 127);
      acc += wy[a] * wx[bb] * row[ix];
    }
  }
  xr[idx] = acc;
}

// ---------------- K6: 3x3 conv 256->80, 8-way channel split ----------------
__global__ __launch_bounds__(256) void k_cate(
    const float* __restrict__ w_cate, float* __restrict__ ws) {
  const int oc = blockIdx.x, tid = threadIdx.x;
  const int pb = blockIdx.y * 800;
  const int sl = blockIdx.z;
  const float* xr = ws + OFF_X0R;
  float* pp = ws + OFF_CPP + ((unsigned)(sl * 80 + oc)) * 1600u;
  const float* __restrict__ wb = w_cate + oc * 2304 + sl * 32 * 9;
  float a0 = 0.f, a1 = 0.f, a2 = 0.f, a3 = 0.f;
  const bool has3 = tid < 32;
  const int p0 = pb + tid, p1 = p0 + 256, p2 = p0 + 512;
  const int p3 = has3 ? p0 + 768 : p0;
  const int b0 = (p0 / 40) * 42 + (p0 % 40);
  const int b1 = (p1 / 40) * 42 + (p1 % 40);
  const int b2 = (p2 / 40) * 42 + (p2 % 40);
  const int b3 = (p3 / 40) * 42 + (p3 % 40);
  const float* xb0 = xr + sl * 32 * 1764;
#pragma unroll 2
  for (int c = 0; c < 32; ++c) {
    const float* xb = xb0 + c * 1764;
    const float* wc = wb + c * 9;
#pragma unroll
    for (int t = 0; t < 9; ++t) {
      const float w = wc[t];
      const int d = (t / 3) * 42 + (t % 3);
      a0 += w * xb[b0 + d];
      a1 += w * xb[b1 + d];
      a2 += w * xb[b2 + d];
      a3 += w * xb[b3 + d];
    }
  }
  pp[p0] = a0;
  pp[p1] = a1;
  pp[p2] = a2;
  if (has3) pp[p3] = a3;
}

// ---------------- K6b: reduce cate partials + bias + sigmoid ---------------
__global__ __launch_bounds__(256) void k_catered(
    const float* __restrict__ b_cate, float* __restrict__ ws) {
  const int idx = blockIdx.x * 256 + threadIdx.x;  // 128000
  const int oc = idx / 1600;
  const float* pp = ws + OFF_CPP;
  float s = b_cate[oc];
#pragma unroll
  for (int sl = 0; sl < 8; ++sl) s += pp[(unsigned)sl * 128000u + idx];
  ws[OFF_CATE + idx] = sigmoidf_(s);
}

// ---------------- K7: points_nms -> out tail -------------------------------
__global__ __launch_bounds__(256) void k_nms(
    const float* __restrict__ ws, float* __restrict__ out) {
  const int idx = blockIdx.x * 256 + threadIdx.x;  // 128000
  const float* cp = ws + OFF_CATE;
  const int r = idx % 1600, y = r / 40, x = r % 40;
  const float v = cp[idx];
  float m = v;
  if (y > 0 && x > 0) m = fmaxf(m, cp[idx - 41]);
  if (y > 0)          m = fmaxf(m, cp[idx - 40]);
  if (x > 0)          m = fmaxf(m, cp[idx - 1]);
  out[SEG_ELEMS + idx] = (m == v) ? v : 0.f;
}

// ---------------- K8: fused dynamic 3-layer MLP + sigmoid ------------------
// POSB=6: grid (16, 96) = 1536 blocks — divides evenly at both 2 and 3
// resident blocks/CU (512 / 768), no tail imbalance.
#define POSB 6
__global__ __launch_bounds__(256, 2) void k_dyn(
    const float* __restrict__ ws, float* __restrict__ out) {
  const int tid = threadIdx.x;
  const float* feat = ws + OFF_FEAT;
  const float* kpT = ws + OFF_KPT;
  const int pb = blockIdx.x * 1024 + tid * 4;
  float4 f[20];
#pragma unroll
  for (int e = 0; e < 20; ++e)
    f[e] = *reinterpret_cast<const float4*>(feat + e * 16384 + pb);
#pragma unroll 1
  for (int np = 0; np < POSB; ++np) {
    const int n = blockIdx.y * POSB + np;
    const float* __restrict__ w = kpT + n * 249;
    // layer 1: 20 -> 8, relu
    float h1x[8], h1y[8], h1z[8], h1w[8];
#pragma unroll
    for (int d = 0; d < 8; ++d) {
      float ax = w[160 + d], ay = ax, az = ax, aw = ax;
#pragma unroll
      for (int e = 0; e < 20; ++e) {
        const float wv = w[d * 20 + e];
        ax += wv * f[e].x; ay += wv * f[e].y;
        az += wv * f[e].z; aw += wv * f[e].w;
      }
      h1x[d] = fmaxf(ax, 0.f); h1y[d] = fmaxf(ay, 0.f);
      h1z[d] = fmaxf(az, 0.f); h1w[d] = fmaxf(aw, 0.f);
    }
    // layer 2: 8 -> 8, relu
    float h2x[8], h2y[8], h2z[8], h2w[8];
#pragma unroll
    for (int d = 0; d < 8; ++d) {
      float ax = w[232 + d], ay = ax, az = ax, aw = ax;
#pragma unroll
      for (int e = 0; e < 8; ++e) {
        const float wv = w[168 + d * 8 + e];
        ax += wv * h1x[e]; ay += wv * h1y[e];
        az += wv * h1z[e]; aw += wv * h1w[e];
      }
      h2x[d] = fmaxf(ax, 0.f); h2y[d] = fmaxf(ay, 0.f);
      h2z[d] = fmaxf(az, 0.f); h2w[d] = fmaxf(aw, 0.f);
    }
    // layer 3: 8 -> 1, sigmoid
    float mx = w[248], my = mx, mz = mx, mw = mx;
#pragma unroll
    for (int e = 0; e < 8; ++e) {
      const float wv = w[240 + e];
      mx += wv * h2x[e]; my += wv * h2y[e];
      mz += wv * h2z[e]; mw += wv * h2w[e];
    }
    float4 rr;
    rr.x = sigmoidf_(mx); rr.y = sigmoidf_(my);
    rr.z = sigmoidf_(mz); rr.w = sigmoidf_(mw);
    *reinterpret_cast<float4*>(out + (size_t)n * 16384 + pb) = rr;
  }
}

// ---------------------------------------------------------------------------
extern "C" void kernel_launch(void* const* d_in, const int* in_sizes, int n_in,
                              void* d_out, int out_size, void* d_ws, size_t ws_size,
                              hipStream_t stream) {
  const float* x0        = (const float*)d_in[0];
  const float* x1        = (const float*)d_in[1];
  const float* x2        = (const float*)d_in[2];
  const float* x3        = (const float*)d_in[3];
  const float* x4        = (const float*)d_in[4];
  const float* mask_feat = (const float*)d_in[5];
  const float* w_ctx     = (const float*)d_in[6];
  const float* b_ctx     = (const float*)d_in[7];
  const float* w_lw      = (const float*)d_in[8];
  const float* b_lw      = (const float*)d_in[9];
  const float* w_cate    = (const float*)d_in[10];
  const float* b_cate    = (const float*)d_in[11];
  float* out = (float*)d_out;
  float* ws  = (float*)d_ws;

  hipLaunchKernelGGL(k_gemm_ys, dim3(341), dim3(256), 0, stream,
                     x0, x1, x2, x3, x4, w_ctx, ws);
  hipLaunchKernelGGL(k_feat, dim3(1280), dim3(256), 0, stream,
                     mask_feat, b_ctx, ws);
  hipLaunchKernelGGL(k_kin, dim3(676), dim3(256), 0, stream, x2, ws);
  hipLaunchKernelGGL(k_kpconv, dim3(249, 8), dim3(256), 0, stream, w_lw, ws);
  hipLaunchKernelGGL(k_kpred, dim3(561), dim3(256), 0, stream, b_lw, ws);
  hipLaunchKernelGGL(k_x0r, dim3(1764), dim3(256), 0, stream, x0, ws);
  hipLaunchKernelGGL(k_cate, dim3(80, 2, 8), dim3(256), 0, stream, w_cate, ws);
  hipLaunchKernelGGL(k_catered, dim3(500), dim3(256), 0, stream, b_cate, ws);
  hipLaunchKernelGGL(k_nms, dim3(500), dim3(256), 0, stream, ws, out);
  hipLaunchKernelGGL(k_dyn, dim3(16, 96), dim3(256), 0, stream, ws, out);
}

// Round 4
// 286.607 us; speedup vs baseline: 1.6933x; 1.0008x over previous
//
#include <hip/hip_runtime.h>

// ---------------------------------------------------------------------------
// AggMaskStarHead: SOLO-style dynamic mask head, fp32 throughout.
//
//  K1 k_gemm_ys : 16x256 GEMM per source at native res, 4-way channel split
//                 within block (1 wave = 1 slice), LDS reduce
//  K2 k_feat    : feat[20][16384] = [mask_feat(4); relu(b + y0 + sum bilin(ys))]
//  K3 k_kin     : x2 (32x32) -> kin (24x24) antialiased, padded 26x26
//  K4 k_kpconv  : 3x3 conv 256->249 over 24x24, 8-way channel split -> partials
//  K4b k_kpred  : sum 8 partials + bias -> kpT[576][249]
//  K5 k_x0r     : x0 (128x128) -> 40x40 antialiased, padded 42x42
//  K6 k_cate    : 3x3 conv 256->80, 8-way channel split -> partials
//  K6b k_catered: sum 8 partials + bias + sigmoid -> cate_pre
//  K7 k_nms     : points_nms -> out tail
//  K8 k_dyn     : fused 3-layer dynamic MLP + sigmoid -> out head
//                 feat held in 80 asm-pinned VGPRs: R2/R3 showed VGPR=76 with
//                 loads sunk into the position loop (2/3 of VALU issue was
//                 reload overhead). launch_bounds(256,2) alone did NOT change
//                 the allocator's choice; the asm liveness pin forces it.
// ---------------------------------------------------------------------------

// workspace float offsets
#define OFF_Y0   0u           // 16*16384
#define OFF_Y1   262144u      // 16*4096
#define OFF_Y2   327680u      // 16*1024
#define OFF_Y3   344064u      // 16*256
#define OFF_Y4   348160u      // 16*64
#define OFF_FEAT 349184u      // 20*16384
#define OFF_KIN  676864u      // 256*676  (26x26 zero-padded)
#define OFF_KPT  849920u      // 576*249
#define OFF_X0R  993344u      // 256*1764 (42x42 zero-padded)
#define OFF_CATE 1444928u     // 80*1600
#define OFF_KPP  1572928u     // 8*249*576 kpconv partials
#define OFF_CPP  2720320u     // 8*80*1600 cate partials
// total 3744320 floats ~= 15 MB

#define SEG_ELEMS 9437184     // 576*128*128

__device__ __forceinline__ float sigmoidf_(float x) {
  return 1.0f / (1.0f + __expf(-x));
}

// ---------------- K1: per-source 16x256 GEMMs (4-way channel split) --------
__global__ __launch_bounds__(256) void k_gemm_ys(
    const float* __restrict__ x0, const float* __restrict__ x1,
    const float* __restrict__ x2, const float* __restrict__ x3,
    const float* __restrict__ x4, const float* __restrict__ w_ctx,
    float* __restrict__ ws) {
  __shared__ float wl[4096];   // [c][o]
  __shared__ float red[4096];  // [slice][o][px]
  const int b = blockIdx.x, tid = threadIdx.x;
  int s, Q, qb;
  const float* xs;
  float* ys;
  if (b < 256)      { s = 0; xs = x0; ys = ws + OFF_Y0; Q = 16384; qb = b * 64; }
  else if (b < 320) { s = 1; xs = x1; ys = ws + OFF_Y1; Q = 4096;  qb = (b - 256) * 64; }
  else if (b < 336) { s = 2; xs = x2; ys = ws + OFF_Y2; Q = 1024;  qb = (b - 320) * 64; }
  else if (b < 340) { s = 3; xs = x3; ys = ws + OFF_Y3; Q = 256;   qb = (b - 336) * 64; }
  else              { s = 4; xs = x4; ys = ws + OFF_Y4; Q = 64;    qb = 0; }
  for (int i = tid; i < 4096; i += 256) {
    const int c = i >> 4, o = i & 15;
    wl[i] = w_ctx[o * 1280 + s * 256 + c];
  }
  __syncthreads();
  const int slice = tid >> 6, px = tid & 63;
  const int q = qb + px;
  float acc[16];
#pragma unroll
  for (int o = 0; o < 16; ++o) acc[o] = 0.f;
  const int c0 = slice * 64;
  for (int c = c0; c < c0 + 64; ++c) {
    const float v = xs[c * Q + q];
    const float* wc = &wl[c * 16];   // wave-uniform -> LDS broadcast
#pragma unroll
    for (int o = 0; o < 16; ++o) acc[o] += wc[o] * v;
  }
#pragma unroll
  for (int o = 0; o < 16; ++o) red[slice * 1024 + o * 64 + px] = acc[o];
  __syncthreads();
  const int og = tid >> 6;  // 4 outputs per thread
#pragma unroll
  for (int j = 0; j < 4; ++j) {
    const int o = og * 4 + j;
    const float v = red[o * 64 + px] + red[1024 + o * 64 + px] +
                    red[2048 + o * 64 + px] + red[3072 + o * 64 + px];
    ys[o * Q + qb + px] = v;
  }
}

// ---------------- K2: build feat = [mask_feat; relu(ctx)] ------------------
__global__ __launch_bounds__(256) void k_feat(
    const float* __restrict__ mask_feat, const float* __restrict__ b_ctx,
    float* __restrict__ ws) {
  const int idx = blockIdx.x * 256 + threadIdx.x;  // 0..327679
  float* feat = ws + OFF_FEAT;
  if (idx < 65536) { feat[idx] = mask_feat[idx]; return; }
  const int r = idx - 65536;
  const int o = r >> 14, p = r & 16383;
  const int y = p >> 7, x = p & 127;
  float v = b_ctx[o] + ws[OFF_Y0 + o * 16384 + p];
  const unsigned offs[4] = {OFF_Y1, OFF_Y2, OFF_Y3, OFF_Y4};
  const int Ss[4] = {64, 32, 16, 8};
#pragma unroll
  for (int s = 0; s < 4; ++s) {
    const int S = Ss[s];
    const float sc = (float)S / 128.0f;
    const float fy = (y + 0.5f) * sc - 0.5f;
    const float fx = (x + 0.5f) * sc - 0.5f;
    const int iy = (int)floorf(fy), ix = (int)floorf(fx);
    const float ty = fy - (float)iy, tx = fx - (float)ix;
    const int y0 = iy < 0 ? 0 : iy;
    const int y1 = (iy + 1 > S - 1) ? S - 1 : iy + 1;
    const int x0 = ix < 0 ? 0 : ix;
    const int x1 = (ix + 1 > S - 1) ? S - 1 : ix + 1;
    const float* yb = ws + offs[s] + o * S * S;
    const float v00 = yb[y0 * S + x0], v01 = yb[y0 * S + x1];
    const float v10 = yb[y1 * S + x0], v11 = yb[y1 * S + x1];
    v += (1.f - ty) * ((1.f - tx) * v00 + tx * v01)
       + ty * ((1.f - tx) * v10 + tx * v11);
  }
  feat[(4 + o) * 16384 + p] = fmaxf(v, 0.f);
}

// ---------------- K3: x2 -> kin 24x24 (antialiased, padded 26x26) ----------
__global__ __launch_bounds__(256) void k_kin(
    const float* __restrict__ x2, float* __restrict__ ws) {
  const int idx = blockIdx.x * 256 + threadIdx.x;  // 256*676
  float* kin = ws + OFF_KIN;
  const int c = idx / 676, r = idx % 676;
  const int py = r / 26, px = r % 26;
  const int oy = py - 1, ox = px - 1;
  if (oy < 0 || oy >= 24 || ox < 0 || ox >= 24) { kin[idx] = 0.f; return; }
  float wy[4], wx[4];
  int iy0, ix0;
  {
    const float s = (oy + 0.5f) * (4.0f / 3.0f) - 0.5f;
    iy0 = (int)floorf(s) - 1;
    float sw = 0.f;
#pragma unroll
    for (int a = 0; a < 4; ++a) {
      const int i = iy0 + a;
      float w = fmaxf(1.0f - fabsf((float)i - s) * 0.75f, 0.f);
      if (i < 0 || i > 31) w = 0.f;
      wy[a] = w; sw += w;
    }
    const float inv = 1.0f / sw;
#pragma unroll
    for (int a = 0; a < 4; ++a) wy[a] *= inv;
  }
  {
    const float s = (ox + 0.5f) * (4.0f / 3.0f) - 0.5f;
    ix0 = (int)floorf(s) - 1;
    float sw = 0.f;
#pragma unroll
    for (int a = 0; a < 4; ++a) {
      const int i = ix0 + a;
      float w = fmaxf(1.0f - fabsf((float)i - s) * 0.75f, 0.f);
      if (i < 0 || i > 31) w = 0.f;
      wx[a] = w; sw += w;
    }
    const float inv = 1.0f / sw;
#pragma unroll
    for (int a = 0; a < 4; ++a) wx[a] *= inv;
  }
  float acc = 0.f;
#pragma unroll
  for (int a = 0; a < 4; ++a) {
    const int iy = min(max(iy0 + a, 0), 31);
    const float* row = x2 + c * 1024 + iy * 32;
#pragma unroll
    for (int bb = 0; bb < 4; ++bb) {
      const int ix = min(max(ix0 + bb, 0), 31);
      acc += wy[a] * wx[bb] * row[ix];
    }
  }
  kin[idx] = acc;
}

// ---------------- K4: 3x3 conv 256->249, 8-way channel split ---------------
__global__ __launch_bounds__(256) void k_kpconv(
    const float* __restrict__ w_lw, float* __restrict__ ws) {
  const int oc = blockIdx.x, sl = blockIdx.y, tid = threadIdx.x;
  const float* kin = ws + OFF_KIN;
  float* pp = ws + OFF_KPP + ((unsigned)(sl * 249 + oc)) * 576u;
  const float* __restrict__ wb = w_lw + oc * 2304 + sl * 32 * 9;
  float a0 = 0.f, a1 = 0.f, a2 = 0.f;
  const int p0 = tid, p1 = tid + 256;
  const bool has2 = tid < 64;
  const int p2 = has2 ? tid + 512 : tid;
  const int b0 = (p0 / 24) * 26 + (p0 % 24);
  const int b1 = (p1 / 24) * 26 + (p1 % 24);
  const int b2 = (p2 / 24) * 26 + (p2 % 24);
  const float* kb = kin + sl * 32 * 676;
#pragma unroll 2
  for (int c = 0; c < 32; ++c) {
    const float* kc = kb + c * 676;
    const float* wc = wb + c * 9;
#pragma unroll
    for (int t = 0; t < 9; ++t) {
      const float w = wc[t];
      const int d = (t / 3) * 26 + (t % 3);
      a0 += w * kc[b0 + d];
      a1 += w * kc[b1 + d];
      a2 += w * kc[b2 + d];
    }
  }
  pp[p0] = a0;
  pp[p1] = a1;
  if (has2) pp[p2] = a2;
}

// ---------------- K4b: reduce kpconv partials -> kpT[576][249] -------------
__global__ __launch_bounds__(256) void k_kpred(
    const float* __restrict__ b_lw, float* __restrict__ ws) {
  const int idx = blockIdx.x * 256 + threadIdx.x;
  if (idx >= 249 * 576) return;
  const int oc = idx / 576, p = idx % 576;
  const float* pp = ws + OFF_KPP;
  float s = b_lw[oc];
#pragma unroll
  for (int sl = 0; sl < 8; ++sl) s += pp[((unsigned)(sl * 249 + oc)) * 576u + p];
  ws[OFF_KPT + (unsigned)p * 249u + oc] = s;
}

// ---------------- K5: x0 -> 40x40 (antialiased, padded 42x42) --------------
__global__ __launch_bounds__(256) void k_x0r(
    const float* __restrict__ x0, float* __restrict__ ws) {
  const int idx = blockIdx.x * 256 + threadIdx.x;  // 256*1764
  float* xr = ws + OFF_X0R;
  const int c = idx / 1764, r = idx % 1764;
  const int py = r / 42, px = r % 42;
  const int oy = py - 1, ox = px - 1;
  if (oy < 0 || oy >= 40 || ox < 0 || ox >= 40) { xr[idx] = 0.f; return; }
  float wy[8], wx[8];
  int iy0, ix0;
  {
    const float s = (oy + 0.5f) * 3.2f - 0.5f;
    iy0 = (int)floorf(s) - 3;
    float sw = 0.f;
#pragma unroll
    for (int a = 0; a < 8; ++a) {
      const int i = iy0 + a;
      float w = fmaxf(1.0f - fabsf((float)i - s) * 0.3125f, 0.f);
      if (i < 0 || i > 127) w = 0.f;
      wy[a] = w; sw += w;
    }
    const float inv = 1.0f / sw;
#pragma unroll
    for (int a = 0; a < 8; ++a) wy[a] *= inv;
  }
  {
    const float s = (ox + 0.5f) * 3.2f - 0.5f;
    ix0 = (int)floorf(s) - 3;
    float sw = 0.f;
#pragma unroll
    for (int a = 0; a < 8; ++a) {
      const int i = ix0 + a;
      float w = fmaxf(1.0f - fabsf((float)i - s) * 0.3125f, 0.f);
      if (i < 0 || i > 127) w = 0.f;
      wx[a] = w; sw += w;
    }
    const float inv = 1.0f / sw;
#pragma unroll
    for (int a = 0; a < 8; ++a) wx[a] *= inv;
  }
  float acc = 0.f;
#pragma unroll
  for (int a = 0; a < 8; ++a) {
    const int iy = min(max(iy0 + a, 0), 127);
    const float* row = x0 + c * 16384 + iy * 128;
#pragma unroll
    for (int bb = 0; bb < 8; ++bb) {
      const int ix = min(max(ix0 + bb, 0), 127);
      acc += wy[a] * wx[bb] * row[ix];
    }
  }
  xr[idx] = acc;
}

// ---------------- K6: 3x3 conv 256->80, 8-way channel split ----------------
__global__ __launch_bounds__(256) void k_cate(
    const float* __restrict__ w_cate, float* __restrict__ ws) {
  const int oc = blockIdx.x, tid = threadIdx.x;
  const int pb = blockIdx.y * 800;
  const int sl = blockIdx.z;
  const float* xr = ws + OFF_X0R;
  float* pp = ws + OFF_CPP + ((unsigned)(sl * 80 + oc)) * 1600u;
  const float* __restrict__ wb = w_cate + oc * 2304 + sl * 32 * 9;
  float a0 = 0.f, a1 = 0.f, a2 = 0.f, a3 = 0.f;
  const bool has3 = tid < 32;
  const int p0 = pb + tid, p1 = p0 + 256, p2 = p0 + 512;
  const int p3 = has3 ? p0 + 768 : p0;
  const int b0 = (p0 / 40) * 42 + (p0 % 40);
  const int b1 = (p1 / 40) * 42 + (p1 % 40);
  const int b2 = (p2 / 40) * 42 + (p2 % 40);
  const int b3 = (p3 / 40) * 42 + (p3 % 40);
  const float* xb0 = xr + sl * 32 * 1764;
#pragma unroll 2
  for (int c = 0; c < 32; ++c) {
    const float* xb = xb0 + c * 1764;
    const float* wc = wb + c * 9;
#pragma unroll
    for (int t = 0; t < 9; ++t) {
      const float w = wc[t];
      const int d = (t / 3) * 42 + (t % 3);
      a0 += w * xb[b0 + d];
      a1 += w * xb[b1 + d];
      a2 += w * xb[b2 + d];
      a3 += w * xb[b3 + d];
    }
  }
  pp[p0] = a0;
  pp[p1] = a1;
  pp[p2] = a2;
  if (has3) pp[p3] = a3;
}

// ---------------- K6b: reduce cate partials + bias + sigmoid ---------------
__global__ __launch_bounds__(256) void k_catered(
    const float* __restrict__ b_cate, float* __restrict__ ws) {
  const int idx = blockIdx.x * 256 + threadIdx.x;  // 128000
  const int oc = idx / 1600;
  const float* pp = ws + OFF_CPP;
  float s = b_cate[oc];
#pragma unroll
  for (int sl = 0; sl < 8; ++sl) s += pp[(unsigned)sl * 128000u + idx];
  ws[OFF_CATE + idx] = sigmoidf_(s);
}

// ---------------- K7: points_nms -> out tail -------------------------------
__global__ __launch_bounds__(256) void k_nms(
    const float* __restrict__ ws, float* __restrict__ out) {
  const int idx = blockIdx.x * 256 + threadIdx.x;  // 128000
  const float* cp = ws + OFF_CATE;
  const int r = idx % 1600, y = r / 40, x = r % 40;
  const float v = cp[idx];
  float m = v;
  if (y > 0 && x > 0) m = fmaxf(m, cp[idx - 41]);
  if (y > 0)          m = fmaxf(m, cp[idx - 40]);
  if (x > 0)          m = fmaxf(m, cp[idx - 1]);
  out[SEG_ELEMS + idx] = (m == v) ? v : 0.f;
}

// ---------------- K8: fused dynamic 3-layer MLP + sigmoid ------------------
// POSB=6: grid (16, 96) = 1536 blocks — divides evenly at 2 blocks/CU.
#define POSB 6
__global__ __launch_bounds__(256, 2) void k_dyn(
    const float* __restrict__ ws, float* __restrict__ out) {
  const int tid = threadIdx.x;
  const float* feat = ws + OFF_FEAT;
  const float* kpT = ws + OFF_KPT;
  const int pb = blockIdx.x * 1024 + tid * 4;
  float fx[20], fy[20], fz[20], fw[20];
#pragma unroll
  for (int e = 0; e < 20; ++e) {
    const float4 v = *reinterpret_cast<const float4*>(feat + e * 16384 + pb);
    fx[e] = v.x; fy[e] = v.y; fz[e] = v.z; fw[e] = v.w;
  }
  // Liveness pin (rule #17): values become opaque asm outputs, so the
  // allocator cannot rematerialize them as loads inside the position loop.
#pragma unroll
  for (int e = 0; e < 20; ++e) {
    asm volatile("" : "+v"(fx[e]), "+v"(fy[e]), "+v"(fz[e]), "+v"(fw[e]));
  }
#pragma unroll 1
  for (int np = 0; np < POSB; ++np) {
    const int n = blockIdx.y * POSB + np;
    const float* __restrict__ w = kpT + n * 249;  // block-uniform -> s_load
    // layer 1: 20 -> 8, relu
    float h1x[8], h1y[8], h1z[8], h1w[8];
#pragma unroll
    for (int d = 0; d < 8; ++d) {
      float ax = w[160 + d], ay = ax, az = ax, aw = ax;
#pragma unroll
      for (int e = 0; e < 20; ++e) {
        const float wv = w[d * 20 + e];
        ax += wv * fx[e]; ay += wv * fy[e];
        az += wv * fz[e]; aw += wv * fw[e];
      }
      h1x[d] = fmaxf(ax, 0.f); h1y[d] = fmaxf(ay, 0.f);
      h1z[d] = fmaxf(az, 0.f); h1w[d] = fmaxf(aw, 0.f);
    }
    // layer 2: 8 -> 8, relu
    float h2x[8], h2y[8], h2z[8], h2w[8];
#pragma unroll
    for (int d = 0; d < 8; ++d) {
      float ax = w[232 + d], ay = ax, az = ax, aw = ax;
#pragma unroll
      for (int e = 0; e < 8; ++e) {
        const float wv = w[168 + d * 8 + e];
        ax += wv * h1x[e]; ay += wv * h1y[e];
        az += wv * h1z[e]; aw += wv * h1w[e];
      }
      h2x[d] = fmaxf(ax, 0.f); h2y[d] = fmaxf(ay, 0.f);
      h2z[d] = fmaxf(az, 0.f); h2w[d] = fmaxf(aw, 0.f);
    }
    // layer 3: 8 -> 1, sigmoid
    float mx = w[248], my = mx, mz = mx, mw = mx;
#pragma unroll
    for (int e = 0; e < 8; ++e) {
      const float wv = w[240 + e];
      mx += wv * h2x[e]; my += wv * h2y[e];
      mz += wv * h2z[e]; mw += wv * h2w[e];
    }
    float4 rr;
    rr.x = sigmoidf_(mx); rr.y = sigmoidf_(my);
    rr.z = sigmoidf_(mz); rr.w = sigmoidf_(mw);
    *reinterpret_cast<float4*>(out + (size_t)n * 16384 + pb) = rr;
  }
}

// ---------------------------------------------------------------------------
extern "C" void kernel_launch(void* const* d_in, const int* in_sizes, int n_in,
                              void* d_out, int out_size, void* d_ws, size_t ws_size,
                              hipStream_t stream) {
  const float* x0        = (const float*)d_in[0];
  const float* x1        = (const float*)d_in[1];
  const float* x2        = (const float*)d_in[2];
  const float* x3        = (const float*)d_in[3];
  const float* x4        = (const float*)d_in[4];
  const float* mask_feat = (const float*)d_in[5];
  const float* w_ctx     = (const float*)d_in[6];
  const float* b_ctx     = (const float*)d_in[7];
  const float* w_lw      = (const float*)d_in[8];
  const float* b_lw      = (const float*)d_in[9];
  const float* w_cate    = (const float*)d_in[10];
  const float* b_cate    = (const float*)d_in[11];
  float* out = (float*)d_out;
  float* ws  = (float*)d_ws;

  hipLaunchKernelGGL(k_gemm_ys, dim3(341), dim3(256), 0, stream,
                     x0, x1, x2, x3, x4, w_ctx, ws);
  hipLaunchKernelGGL(k_feat, dim3(1280), dim3(256), 0, stream,
                     mask_feat, b_ctx, ws);
  hipLaunchKernelGGL(k_kin, dim3(676), dim3(256), 0, stream, x2, ws);
  hipLaunchKernelGGL(k_kpconv, dim3(249, 8), dim3(256), 0, stream, w_lw, ws);
  hipLaunchKernelGGL(k_kpred, dim3(561), dim3(256), 0, stream, b_lw, ws);
  hipLaunchKernelGGL(k_x0r, dim3(1764), dim3(256), 0, stream, x0, ws);
  hipLaunchKernelGGL(k_cate, dim3(80, 2, 8), dim3(256), 0, stream, w_cate, ws);
  hipLaunchKernelGGL(k_catered, dim3(500), dim3(256), 0, stream, b_cate, ws);
  hipLaunchKernelGGL(k_nms, dim3(500), dim3(256), 0, stream, ws, out);
  hipLaunchKernelGGL(k_dyn, dim3(16, 96), dim3(256), 0, stream, ws, out);
}

// Round 5
// 280.693 us; speedup vs baseline: 1.7289x; 1.0211x over previous
//
#include <hip/hip_runtime.h>

// ---------------------------------------------------------------------------
// AggMaskStarHead: SOLO-style dynamic mask head, fp32 throughout.
//
//  K1 k_gemm_ys : 16x256 GEMM per source at native res, 4-way channel split
//  K2 k_feat    : feat[20][16384] = [mask_feat(4); relu(b + y0 + sum bilin(ys))]
//  K3 k_kin     : x2 (32x32) -> kin (24x24) antialiased, padded 26x26
//  K4 k_kpconv  : 3x3 conv 256->249 over 24x24, 8-way channel split -> partials
//  K4b k_kpred  : sum 8 partials + bias -> kpT[576][249]
//  K5 k_x0r     : x0 (128x128) -> 40x40 antialiased, padded 42x42
//  K6 k_cate    : 3x3 conv 256->80, 8-way channel split -> partials
//  K6b k_catered: sum 8 partials + bias + sigmoid -> cate_pre
//  K7 k_nms     : points_nms -> out tail
//  K8 k_dyn     : fused 3-layer dynamic MLP + sigmoid -> out head
//                 v2: feat tile staged in LDS (40 KB, [20][512], 2 px/thread).
//                 R2-R4 history: allocator pinned VGPR=76 and sank the 80-reg
//                 feat working set into the position loop (launch_bounds and
//                 asm liveness pins both failed to move it). LDS staging makes
//                 the reuse structural: ds_read_b64 per channel per position,
//                 ~120cy hidden under ~930 FMA cycles; registers hold only
//                 h1/h2 (~60 VGPR) -> nothing to spill or sink.
// ---------------------------------------------------------------------------

// workspace float offsets
#define OFF_Y0   0u           // 16*16384
#define OFF_Y1   262144u      // 16*4096
#define OFF_Y2   327680u      // 16*1024
#define OFF_Y3   344064u      // 16*256
#define OFF_Y4   348160u      // 16*64
#define OFF_FEAT 349184u      // 20*16384
#define OFF_KIN  676864u      // 256*676  (26x26 zero-padded)
#define OFF_KPT  849920u      // 576*249
#define OFF_X0R  993344u      // 256*1764 (42x42 zero-padded)
#define OFF_CATE 1444928u     // 80*1600
#define OFF_KPP  1572928u     // 8*249*576 kpconv partials
#define OFF_CPP  2720320u     // 8*80*1600 cate partials
// total 3744320 floats ~= 15 MB

#define SEG_ELEMS 9437184     // 576*128*128

__device__ __forceinline__ float sigmoidf_(float x) {
  return 1.0f / (1.0f + __expf(-x));
}

// ---------------- K1: per-source 16x256 GEMMs (4-way channel split) --------
__global__ __launch_bounds__(256) void k_gemm_ys(
    const float* __restrict__ x0, const float* __restrict__ x1,
    const float* __restrict__ x2, const float* __restrict__ x3,
    const float* __restrict__ x4, const float* __restrict__ w_ctx,
    float* __restrict__ ws) {
  __shared__ float wl[4096];   // [c][o]
  __shared__ float red[4096];  // [slice][o][px]
  const int b = blockIdx.x, tid = threadIdx.x;
  int s, Q, qb;
  const float* xs;
  float* ys;
  if (b < 256)      { s = 0; xs = x0; ys = ws + OFF_Y0; Q = 16384; qb = b * 64; }
  else if (b < 320) { s = 1; xs = x1; ys = ws + OFF_Y1; Q = 4096;  qb = (b - 256) * 64; }
  else if (b < 336) { s = 2; xs = x2; ys = ws + OFF_Y2; Q = 1024;  qb = (b - 320) * 64; }
  else if (b < 340) { s = 3; xs = x3; ys = ws + OFF_Y3; Q = 256;   qb = (b - 336) * 64; }
  else              { s = 4; xs = x4; ys = ws + OFF_Y4; Q = 64;    qb = 0; }
  for (int i = tid; i < 4096; i += 256) {
    const int c = i >> 4, o = i & 15;
    wl[i] = w_ctx[o * 1280 + s * 256 + c];
  }
  __syncthreads();
  const int slice = tid >> 6, px = tid & 63;
  const int q = qb + px;
  float acc[16];
#pragma unroll
  for (int o = 0; o < 16; ++o) acc[o] = 0.f;
  const int c0 = slice * 64;
  for (int c = c0; c < c0 + 64; ++c) {
    const float v = xs[c * Q + q];
    const float* wc = &wl[c * 16];   // wave-uniform -> LDS broadcast
#pragma unroll
    for (int o = 0; o < 16; ++o) acc[o] += wc[o] * v;
  }
#pragma unroll
  for (int o = 0; o < 16; ++o) red[slice * 1024 + o * 64 + px] = acc[o];
  __syncthreads();
  const int og = tid >> 6;  // 4 outputs per thread
#pragma unroll
  for (int j = 0; j < 4; ++j) {
    const int o = og * 4 + j;
    const float v = red[o * 64 + px] + red[1024 + o * 64 + px] +
                    red[2048 + o * 64 + px] + red[3072 + o * 64 + px];
    ys[o * Q + qb + px] = v;
  }
}

// ---------------- K2: build feat = [mask_feat; relu(ctx)] ------------------
__global__ __launch_bounds__(256) void k_feat(
    const float* __restrict__ mask_feat, const float* __restrict__ b_ctx,
    float* __restrict__ ws) {
  const int idx = blockIdx.x * 256 + threadIdx.x;  // 0..327679
  float* feat = ws + OFF_FEAT;
  if (idx < 65536) { feat[idx] = mask_feat[idx]; return; }
  const int r = idx - 65536;
  const int o = r >> 14, p = r & 16383;
  const int y = p >> 7, x = p & 127;
  float v = b_ctx[o] + ws[OFF_Y0 + o * 16384 + p];
  const unsigned offs[4] = {OFF_Y1, OFF_Y2, OFF_Y3, OFF_Y4};
  const int Ss[4] = {64, 32, 16, 8};
#pragma unroll
  for (int s = 0; s < 4; ++s) {
    const int S = Ss[s];
    const float sc = (float)S / 128.0f;
    const float fy = (y + 0.5f) * sc - 0.5f;
    const float fx = (x + 0.5f) * sc - 0.5f;
    const int iy = (int)floorf(fy), ix = (int)floorf(fx);
    const float ty = fy - (float)iy, tx = fx - (float)ix;
    const int y0 = iy < 0 ? 0 : iy;
    const int y1 = (iy + 1 > S - 1) ? S - 1 : iy + 1;
    const int x0 = ix < 0 ? 0 : ix;
    const int x1 = (ix + 1 > S - 1) ? S - 1 : ix + 1;
    const float* yb = ws + offs[s] + o * S * S;
    const float v00 = yb[y0 * S + x0], v01 = yb[y0 * S + x1];
    const float v10 = yb[y1 * S + x0], v11 = yb[y1 * S + x1];
    v += (1.f - ty) * ((1.f - tx) * v00 + tx * v01)
       + ty * ((1.f - tx) * v10 + tx * v11);
  }
  feat[(4 + o) * 16384 + p] = fmaxf(v, 0.f);
}

// ---------------- K3: x2 -> kin 24x24 (antialiased, padded 26x26) ----------
__global__ __launch_bounds__(256) void k_kin(
    const float* __restrict__ x2, float* __restrict__ ws) {
  const int idx = blockIdx.x * 256 + threadIdx.x;  // 256*676
  float* kin = ws + OFF_KIN;
  const int c = idx / 676, r = idx % 676;
  const int py = r / 26, px = r % 26;
  const int oy = py - 1, ox = px - 1;
  if (oy < 0 || oy >= 24 || ox < 0 || ox >= 24) { kin[idx] = 0.f; return; }
  float wy[4], wx[4];
  int iy0, ix0;
  {
    const float s = (oy + 0.5f) * (4.0f / 3.0f) - 0.5f;
    iy0 = (int)floorf(s) - 1;
    float sw = 0.f;
#pragma unroll
    for (int a = 0; a < 4; ++a) {
      const int i = iy0 + a;
      float w = fmaxf(1.0f - fabsf((float)i - s) * 0.75f, 0.f);
      if (i < 0 || i > 31) w = 0.f;
      wy[a] = w; sw += w;
    }
    const float inv = 1.0f / sw;
#pragma unroll
    for (int a = 0; a < 4; ++a) wy[a] *= inv;
  }
  {
    const float s = (ox + 0.5f) * (4.0f / 3.0f) - 0.5f;
    ix0 = (int)floorf(s) - 1;
    float sw = 0.f;
#pragma unroll
    for (int a = 0; a < 4; ++a) {
      const int i = ix0 + a;
      float w = fmaxf(1.0f - fabsf((float)i - s) * 0.75f, 0.f);
      if (i < 0 || i > 31) w = 0.f;
      wx[a] = w; sw += w;
    }
    const float inv = 1.0f / sw;
#pragma unroll
    for (int a = 0; a < 4; ++a) wx[a] *= inv;
  }
  float acc = 0.f;
#pragma unroll
  for (int a = 0; a < 4; ++a) {
    const int iy = min(max(iy0 + a, 0), 31);
    const float* row = x2 + c * 1024 + iy * 32;
#pragma unroll
    for (int bb = 0; bb < 4; ++bb) {
      const int ix = min(max(ix0 + bb, 0), 31);
      acc += wy[a] * wx[bb] * row[ix];
    }
  }
  kin[idx] = acc;
}

// ---------------- K4: 3x3 conv 256->249, 8-way channel split ---------------
__global__ __launch_bounds__(256) void k_kpconv(
    const float* __restrict__ w_lw, float* __restrict__ ws) {
  const int oc = blockIdx.x, sl = blockIdx.y, tid = threadIdx.x;
  const float* kin = ws + OFF_KIN;
  float* pp = ws + OFF_KPP + ((unsigned)(sl * 249 + oc)) * 576u;
  const float* __restrict__ wb = w_lw + oc * 2304 + sl * 32 * 9;
  float a0 = 0.f, a1 = 0.f, a2 = 0.f;
  const int p0 = tid, p1 = tid + 256;
  const bool has2 = tid < 64;
  const int p2 = has2 ? tid + 512 : tid;
  const int b0 = (p0 / 24) * 26 + (p0 % 24);
  const int b1 = (p1 / 24) * 26 + (p1 % 24);
  const int b2 = (p2 / 24) * 26 + (p2 % 24);
  const float* kb = kin + sl * 32 * 676;
#pragma unroll 2
  for (int c = 0; c < 32; ++c) {
    const float* kc = kb + c * 676;
    const float* wc = wb + c * 9;
#pragma unroll
    for (int t = 0; t < 9; ++t) {
      const float w = wc[t];
      const int d = (t / 3) * 26 + (t % 3);
      a0 += w * kc[b0 + d];
      a1 += w * kc[b1 + d];
      a2 += w * kc[b2 + d];
    }
  }
  pp[p0] = a0;
  pp[p1] = a1;
  if (has2) pp[p2] = a2;
}

// ---------------- K4b: reduce kpconv partials -> kpT[576][249] -------------
__global__ __launch_bounds__(256) void k_kpred(
    const float* __restrict__ b_lw, float* __restrict__ ws) {
  const int idx = blockIdx.x * 256 + threadIdx.x;
  if (idx >= 249 * 576) return;
  const int oc = idx / 576, p = idx % 576;
  const float* pp = ws + OFF_KPP;
  float s = b_lw[oc];
#pragma unroll
  for (int sl = 0; sl < 8; ++sl) s += pp[((unsigned)(sl * 249 + oc)) * 576u + p];
  ws[OFF_KPT + (unsigned)p * 249u + oc] = s;
}

// ---------------- K5: x0 -> 40x40 (antialiased, padded 42x42) --------------
__global__ __launch_bounds__(256) void k_x0r(
    const float* __restrict__ x0, float* __restrict__ ws) {
  const int idx = blockIdx.x * 256 + threadIdx.x;  // 256*1764
  float* xr = ws + OFF_X0R;
  const int c = idx / 1764, r = idx % 1764;
  const int py = r / 42, px = r % 42;
  const int oy = py - 1, ox = px - 1;
  if (oy < 0 || oy >= 40 || ox < 0 || ox >= 40) { xr[idx] = 0.f; return; }
  float wy[8], wx[8];
  int iy0, ix0;
  {
    const float s = (oy + 0.5f) * 3.2f - 0.5f;
    iy0 = (int)floorf(s) - 3;
    float sw = 0.f;
#pragma unroll
    for (int a = 0; a < 8; ++a) {
      const int i = iy0 + a;
      float w = fmaxf(1.0f - fabsf((float)i - s) * 0.3125f, 0.f);
      if (i < 0 || i > 127) w = 0.f;
      wy[a] = w; sw += w;
    }
    const float inv = 1.0f / sw;
#pragma unroll
    for (int a = 0; a < 8; ++a) wy[a] *= inv;
  }
  {
    const float s = (ox + 0.5f) * 3.2f - 0.5f;
    ix0 = (int)floorf(s) - 3;
    float sw = 0.f;
#pragma unroll
    for (int a = 0; a < 8; ++a) {
      const int i = ix0 + a;
      float w = fmaxf(1.0f - fabsf((float)i - s) * 0.3125f, 0.f);
      if (i < 0 || i > 127) w = 0.f;
      wx[a] = w; sw += w;
    }
    const float inv = 1.0f / sw;
#pragma unroll
    for (int a = 0; a < 8; ++a) wx[a] *= inv;
  }
  float acc = 0.f;
#pragma unroll
  for (int a = 0; a < 8; ++a) {
    const int iy = min(max(iy0 + a, 0), 127);
    const float* row = x0 + c * 16384 + iy * 128;
#pragma unroll
    for (int bb = 0; bb < 8; ++bb) {
      const int ix = min(max(ix0 + bb, 0), 127);
      acc += wy[a] * wx[bb] * row[ix];
    }
  }
  xr[idx] = acc;
}

// ---------------- K6: 3x3 conv 256->80, 8-way channel split ----------------
__global__ __launch_bounds__(256) void k_cate(
    const float* __restrict__ w_cate, float* __restrict__ ws) {
  const int oc = blockIdx.x, tid = threadIdx.x;
  const int pb = blockIdx.y * 800;
  const int sl = blockIdx.z;
  const float* xr = ws + OFF_X0R;
  float* pp = ws + OFF_CPP + ((unsigned)(sl * 80 + oc)) * 1600u;
  const float* __restrict__ wb = w_cate + oc * 2304 + sl * 32 * 9;
  float a0 = 0.f, a1 = 0.f, a2 = 0.f, a3 = 0.f;
  const bool has3 = tid < 32;
  const int p0 = pb + tid, p1 = p0 + 256, p2 = p0 + 512;
  const int p3 = has3 ? p0 + 768 : p0;
  const int b0 = (p0 / 40) * 42 + (p0 % 40);
  const int b1 = (p1 / 40) * 42 + (p1 % 40);
  const int b2 = (p2 / 40) * 42 + (p2 % 40);
  const int b3 = (p3 / 40) * 42 + (p3 % 40);
  const float* xb0 = xr + sl * 32 * 1764;
#pragma unroll 2
  for (int c = 0; c < 32; ++c) {
    const float* xb = xb0 + c * 1764;
    const float* wc = wb + c * 9;
#pragma unroll
    for (int t = 0; t < 9; ++t) {
      const float w = wc[t];
      const int d = (t / 3) * 42 + (t % 3);
      a0 += w * xb[b0 + d];
      a1 += w * xb[b1 + d];
      a2 += w * xb[b2 + d];
      a3 += w * xb[b3 + d];
    }
  }
  pp[p0] = a0;
  pp[p1] = a1;
  pp[p2] = a2;
  if (has3) pp[p3] = a3;
}

// ---------------- K6b: reduce cate partials + bias + sigmoid ---------------
__global__ __launch_bounds__(256) void k_catered(
    const float* __restrict__ b_cate, float* __restrict__ ws) {
  const int idx = blockIdx.x * 256 + threadIdx.x;  // 128000
  const int oc = idx / 1600;
  const float* pp = ws + OFF_CPP;
  float s = b_cate[oc];
#pragma unroll
  for (int sl = 0; sl < 8; ++sl) s += pp[(unsigned)sl * 128000u + idx];
  ws[OFF_CATE + idx] = sigmoidf_(s);
}

// ---------------- K7: points_nms -> out tail -------------------------------
__global__ __launch_bounds__(256) void k_nms(
    const float* __restrict__ ws, float* __restrict__ out) {
  const int idx = blockIdx.x * 256 + threadIdx.x;  // 128000
  const float* cp = ws + OFF_CATE;
  const int r = idx % 1600, y = r / 40, x = r % 40;
  const float v = cp[idx];
  float m = v;
  if (y > 0 && x > 0) m = fmaxf(m, cp[idx - 41]);
  if (y > 0)          m = fmaxf(m, cp[idx - 40]);
  if (x > 0)          m = fmaxf(m, cp[idx - 1]);
  out[SEG_ELEMS + idx] = (m == v) ? v : 0.f;
}

// ---------------- K8 v2: dynamic MLP, feat tile in LDS ---------------------
// 256 thr, 2 px/thread, tile = 512 px, LDS 40 KB -> 4 blocks/CU.
// POSB=9 -> grid (32, 64) = 2048 blocks = exactly 2 residency rounds.
#define POSB 9
__global__ __launch_bounds__(256, 4) void k_dyn(
    const float* __restrict__ ws, float* __restrict__ out) {
  __shared__ float fl[20][512];  // 40 KB
  const int tid = threadIdx.x;
  const float* feat = ws + OFF_FEAT;
  const float* kpT = ws + OFF_KPT;
  const int pb = blockIdx.x * 512;
  // stage feat tile (coalesced float2 per thread per channel)
#pragma unroll
  for (int e = 0; e < 20; ++e) {
    const float2 v =
        *reinterpret_cast<const float2*>(feat + e * 16384 + pb + tid * 2);
    *reinterpret_cast<float2*>(&fl[e][tid * 2]) = v;
  }
  __syncthreads();
#pragma unroll 1
  for (int np = 0; np < POSB; ++np) {
    const int n = blockIdx.y * POSB + np;
    const float* __restrict__ w = kpT + (unsigned)n * 249u;  // uniform -> s_load
    // layer 1: 20 -> 8, relu; stream feat channels from LDS
    float h1a[8], h1b[8];
#pragma unroll
    for (int d = 0; d < 8; ++d) { h1a[d] = w[160 + d]; h1b[d] = h1a[d]; }
#pragma unroll
    for (int e = 0; e < 20; ++e) {
      const float2 v = *reinterpret_cast<const float2*>(&fl[e][tid * 2]);
#pragma unroll
      for (int d = 0; d < 8; ++d) {
        const float wv = w[d * 20 + e];
        h1a[d] += wv * v.x;
        h1b[d] += wv * v.y;
      }
    }
#pragma unroll
    for (int d = 0; d < 8; ++d) {
      h1a[d] = fmaxf(h1a[d], 0.f);
      h1b[d] = fmaxf(h1b[d], 0.f);
    }
    // layer 2: 8 -> 8, relu
    float h2a[8], h2b[8];
#pragma unroll
    for (int d = 0; d < 8; ++d) {
      float aa = w[232 + d], ab = aa;
#pragma unroll
      for (int e = 0; e < 8; ++e) {
        const float wv = w[168 + d * 8 + e];
        aa += wv * h1a[e];
        ab += wv * h1b[e];
      }
      h2a[d] = fmaxf(aa, 0.f);
      h2b[d] = fmaxf(ab, 0.f);
    }
    // layer 3: 8 -> 1, sigmoid
    float ma = w[248], mb = ma;
#pragma unroll
    for (int e = 0; e < 8; ++e) {
      const float wv = w[240 + e];
      ma += wv * h2a[e];
      mb += wv * h2b[e];
    }
    float2 rr;
    rr.x = sigmoidf_(ma);
    rr.y = sigmoidf_(mb);
    *reinterpret_cast<float2*>(out + (size_t)n * 16384 + pb + tid * 2) = rr;
  }
}

// ---------------------------------------------------------------------------
extern "C" void kernel_launch(void* const* d_in, const int* in_sizes, int n_in,
                              void* d_out, int out_size, void* d_ws, size_t ws_size,
                              hipStream_t stream) {
  const float* x0        = (const float*)d_in[0];
  const float* x1        = (const float*)d_in[1];
  const float* x2        = (const float*)d_in[2];
  const float* x3        = (const float*)d_in[3];
  const float* x4        = (const float*)d_in[4];
  const float* mask_feat = (const float*)d_in[5];
  const float* w_ctx     = (const float*)d_in[6];
  const float* b_ctx     = (const float*)d_in[7];
  const float* w_lw      = (const float*)d_in[8];
  const float* b_lw      = (const float*)d_in[9];
  const float* w_cate    = (const float*)d_in[10];
  const float* b_cate    = (const float*)d_in[11];
  float* out = (float*)d_out;
  float* ws  = (float*)d_ws;

  hipLaunchKernelGGL(k_gemm_ys, dim3(341), dim3(256), 0, stream,
                     x0, x1, x2, x3, x4, w_ctx, ws);
  hipLaunchKernelGGL(k_feat, dim3(1280), dim3(256), 0, stream,
                     mask_feat, b_ctx, ws);
  hipLaunchKernelGGL(k_kin, dim3(676), dim3(256), 0, stream, x2, ws);
  hipLaunchKernelGGL(k_kpconv, dim3(249, 8), dim3(256), 0, stream, w_lw, ws);
  hipLaunchKernelGGL(k_kpred, dim3(561), dim3(256), 0, stream, b_lw, ws);
  hipLaunchKernelGGL(k_x0r, dim3(1764), dim3(256), 0, stream, x0, ws);
  hipLaunchKernelGGL(k_cate, dim3(80, 2, 8), dim3(256), 0, stream, w_cate, ws);
  hipLaunchKernelGGL(k_catered, dim3(500), dim3(256), 0, stream, b_cate, ws);
  hipLaunchKernelGGL(k_nms, dim3(500), dim3(256), 0, stream, ws, out);
  hipLaunchKernelGGL(k_dyn, dim3(32, 64), dim3(256), 0, stream, ws, out);
}

// Round 6
// 280.206 us; speedup vs baseline: 1.7319x; 1.0017x over previous
//
#include <hip/hip_runtime.h>

// ---------------------------------------------------------------------------
// AggMaskStarHead: SOLO-style dynamic mask head, fp32 throughout.
//
//  K1 k_gemm_ys : 16x256 GEMM per source at native res, 4-way channel split
//  K2 k_feat    : feat[20][16384] = [mask_feat(4); relu(b + y0 + sum bilin(ys))]
//  K3 k_kin     : x2 (32x32) -> kin (24x24) antialiased, padded 26x26
//  K4 k_kpconv  : 3x3 conv 256->249 over 24x24, 8-way channel split -> partials
//  K4b k_kpred  : sum 8 partials + bias -> kpT[576][249], TRANSPOSED per-pos
//                 layout: W0 as [e][d] (e*8+d), b0, W1 as [e][d] (168+e*8+d),
//                 b1, w2, b2 — contiguous float4 chunks for LDS b128 reads.
//  K5 k_x0r     : x0 (128x128) -> 40x40 antialiased, padded 42x42
//  K6 k_cate    : 3x3 conv 256->80, 8-way channel split -> partials
//  K6b k_catered: sum 8 partials + bias + sigmoid -> cate_pre
//  K7 k_nms     : points_nms -> out tail
//  K8 k_dyn     : fused 3-layer dynamic MLP + sigmoid -> out head
//                 v3: feat tile (40KB) AND position weights (12KB) in LDS.
//                 R5 evidence: feat-in-LDS alone left 111µs with ~3x the
//                 pure-FMA VALU issue — the per-position weight reads were
//                 per-lane VMEM with address arithmetic, not s_loads.
//                 Uniform-address ds_read_b128 broadcasts (free, m136) with
//                 zero per-lane addressing -> inner loop is FMA + broadcast.
// ---------------------------------------------------------------------------

// workspace float offsets
#define OFF_Y0   0u           // 16*16384
#define OFF_Y1   262144u      // 16*4096
#define OFF_Y2   327680u      // 16*1024
#define OFF_Y3   344064u      // 16*256
#define OFF_Y4   348160u      // 16*64
#define OFF_FEAT 349184u      // 20*16384
#define OFF_KIN  676864u      // 256*676  (26x26 zero-padded)
#define OFF_KPT  849920u      // 576*249
#define OFF_X0R  993344u      // 256*1764 (42x42 zero-padded)
#define OFF_CATE 1444928u     // 80*1600
#define OFF_KPP  1572928u     // 8*249*576 kpconv partials
#define OFF_CPP  2720320u     // 8*80*1600 cate partials
// total 3744320 floats ~= 15 MB

#define SEG_ELEMS 9437184     // 576*128*128

__device__ __forceinline__ float sigmoidf_(float x) {
  return 1.0f / (1.0f + __expf(-x));
}

// ---------------- K1: per-source 16x256 GEMMs (4-way channel split) --------
__global__ __launch_bounds__(256) void k_gemm_ys(
    const float* __restrict__ x0, const float* __restrict__ x1,
    const float* __restrict__ x2, const float* __restrict__ x3,
    const float* __restrict__ x4, const float* __restrict__ w_ctx,
    float* __restrict__ ws) {
  __shared__ float wl[4096];   // [c][o]
  __shared__ float red[4096];  // [slice][o][px]
  const int b = blockIdx.x, tid = threadIdx.x;
  int s, Q, qb;
  const float* xs;
  float* ys;
  if (b < 256)      { s = 0; xs = x0; ys = ws + OFF_Y0; Q = 16384; qb = b * 64; }
  else if (b < 320) { s = 1; xs = x1; ys = ws + OFF_Y1; Q = 4096;  qb = (b - 256) * 64; }
  else if (b < 336) { s = 2; xs = x2; ys = ws + OFF_Y2; Q = 1024;  qb = (b - 320) * 64; }
  else if (b < 340) { s = 3; xs = x3; ys = ws + OFF_Y3; Q = 256;   qb = (b - 336) * 64; }
  else              { s = 4; xs = x4; ys = ws + OFF_Y4; Q = 64;    qb = 0; }
  for (int i = tid; i < 4096; i += 256) {
    const int c = i >> 4, o = i & 15;
    wl[i] = w_ctx[o * 1280 + s * 256 + c];
  }
  __syncthreads();
  const int slice = tid >> 6, px = tid & 63;
  const int q = qb + px;
  float acc[16];
#pragma unroll
  for (int o = 0; o < 16; ++o) acc[o] = 0.f;
  const int c0 = slice * 64;
  for (int c = c0; c < c0 + 64; ++c) {
    const float v = xs[c * Q + q];
    const float* wc = &wl[c * 16];   // wave-uniform -> LDS broadcast
#pragma unroll
    for (int o = 0; o < 16; ++o) acc[o] += wc[o] * v;
  }
#pragma unroll
  for (int o = 0; o < 16; ++o) red[slice * 1024 + o * 64 + px] = acc[o];
  __syncthreads();
  const int og = tid >> 6;  // 4 outputs per thread
#pragma unroll
  for (int j = 0; j < 4; ++j) {
    const int o = og * 4 + j;
    const float v = red[o * 64 + px] + red[1024 + o * 64 + px] +
                    red[2048 + o * 64 + px] + red[3072 + o * 64 + px];
    ys[o * Q + qb + px] = v;
  }
}

// ---------------- K2: build feat = [mask_feat; relu(ctx)] ------------------
__global__ __launch_bounds__(256) void k_feat(
    const float* __restrict__ mask_feat, const float* __restrict__ b_ctx,
    float* __restrict__ ws) {
  const int idx = blockIdx.x * 256 + threadIdx.x;  // 0..327679
  float* feat = ws + OFF_FEAT;
  if (idx < 65536) { feat[idx] = mask_feat[idx]; return; }
  const int r = idx - 65536;
  const int o = r >> 14, p = r & 16383;
  const int y = p >> 7, x = p & 127;
  float v = b_ctx[o] + ws[OFF_Y0 + o * 16384 + p];
  const unsigned offs[4] = {OFF_Y1, OFF_Y2, OFF_Y3, OFF_Y4};
  const int Ss[4] = {64, 32, 16, 8};
#pragma unroll
  for (int s = 0; s < 4; ++s) {
    const int S = Ss[s];
    const float sc = (float)S / 128.0f;
    const float fy = (y + 0.5f) * sc - 0.5f;
    const float fx = (x + 0.5f) * sc - 0.5f;
    const int iy = (int)floorf(fy), ix = (int)floorf(fx);
    const float ty = fy - (float)iy, tx = fx - (float)ix;
    const int y0 = iy < 0 ? 0 : iy;
    const int y1 = (iy + 1 > S - 1) ? S - 1 : iy + 1;
    const int x0 = ix < 0 ? 0 : ix;
    const int x1 = (ix + 1 > S - 1) ? S - 1 : ix + 1;
    const float* yb = ws + offs[s] + o * S * S;
    const float v00 = yb[y0 * S + x0], v01 = yb[y0 * S + x1];
    const float v10 = yb[y1 * S + x0], v11 = yb[y1 * S + x1];
    v += (1.f - ty) * ((1.f - tx) * v00 + tx * v01)
       + ty * ((1.f - tx) * v10 + tx * v11);
  }
  feat[(4 + o) * 16384 + p] = fmaxf(v, 0.f);
}

// ---------------- K3: x2 -> kin 24x24 (antialiased, padded 26x26) ----------
__global__ __launch_bounds__(256) void k_kin(
    const float* __restrict__ x2, float* __restrict__ ws) {
  const int idx = blockIdx.x * 256 + threadIdx.x;  // 256*676
  float* kin = ws + OFF_KIN;
  const int c = idx / 676, r = idx % 676;
  const int py = r / 26, px = r % 26;
  const int oy = py - 1, ox = px - 1;
  if (oy < 0 || oy >= 24 || ox < 0 || ox >= 24) { kin[idx] = 0.f; return; }
  float wy[4], wx[4];
  int iy0, ix0;
  {
    const float s = (oy + 0.5f) * (4.0f / 3.0f) - 0.5f;
    iy0 = (int)floorf(s) - 1;
    float sw = 0.f;
#pragma unroll
    for (int a = 0; a < 4; ++a) {
      const int i = iy0 + a;
      float w = fmaxf(1.0f - fabsf((float)i - s) * 0.75f, 0.f);
      if (i < 0 || i > 31) w = 0.f;
      wy[a] = w; sw += w;
    }
    const float inv = 1.0f / sw;
#pragma unroll
    for (int a = 0; a < 4; ++a) wy[a] *= inv;
  }
  {
    const float s = (ox + 0.5f) * (4.0f / 3.0f) - 0.5f;
    ix0 = (int)floorf(s) - 1;
    float sw = 0.f;
#pragma unroll
    for (int a = 0; a < 4; ++a) {
      const int i = ix0 + a;
      float w = fmaxf(1.0f - fabsf((float)i - s) * 0.75f, 0.f);
      if (i < 0 || i > 31) w = 0.f;
      wx[a] = w; sw += w;
    }
    const float inv = 1.0f / sw;
#pragma unroll
    for (int a = 0; a < 4; ++a) wx[a] *= inv;
  }
  float acc = 0.f;
#pragma unroll
  for (int a = 0; a < 4; ++a) {
    const int iy = min(max(iy0 + a, 0), 31);
    const float* row = x2 + c * 1024 + iy * 32;
#pragma unroll
    for (int bb = 0; bb < 4; ++bb) {
      const int ix = min(max(ix0 + bb, 0), 31);
      acc += wy[a] * wx[bb] * row[ix];
    }
  }
  kin[idx] = acc;
}

// ---------------- K4: 3x3 conv 256->249, 8-way channel split ---------------
__global__ __launch_bounds__(256) void k_kpconv(
    const float* __restrict__ w_lw, float* __restrict__ ws) {
  const int oc = blockIdx.x, sl = blockIdx.y, tid = threadIdx.x;
  const float* kin = ws + OFF_KIN;
  float* pp = ws + OFF_KPP + ((unsigned)(sl * 249 + oc)) * 576u;
  const float* __restrict__ wb = w_lw + oc * 2304 + sl * 32 * 9;
  float a0 = 0.f, a1 = 0.f, a2 = 0.f;
  const int p0 = tid, p1 = tid + 256;
  const bool has2 = tid < 64;
  const int p2 = has2 ? tid + 512 : tid;
  const int b0 = (p0 / 24) * 26 + (p0 % 24);
  const int b1 = (p1 / 24) * 26 + (p1 % 24);
  const int b2 = (p2 / 24) * 26 + (p2 % 24);
  const float* kb = kin + sl * 32 * 676;
#pragma unroll 2
  for (int c = 0; c < 32; ++c) {
    const float* kc = kb + c * 676;
    const float* wc = wb + c * 9;
#pragma unroll
    for (int t = 0; t < 9; ++t) {
      const float w = wc[t];
      const int d = (t / 3) * 26 + (t % 3);
      a0 += w * kc[b0 + d];
      a1 += w * kc[b1 + d];
      a2 += w * kc[b2 + d];
    }
  }
  pp[p0] = a0;
  pp[p1] = a1;
  if (has2) pp[p2] = a2;
}

// ---------------- K4b: reduce kpconv partials -> kpT[576][249] -------------
// Writes the TRANSPOSED per-position layout consumed by k_dyn v3:
//   oc in [0,160):   d=oc/20, e=oc%20   -> e*8+d        (W0 as [e][d])
//   oc in [168,232): t=oc-168; d=t/8, e=t%8 -> 168+e*8+d (W1 as [e][d])
//   else unchanged (b0 @160..167, b1 @232..239, w2 @240..247, b2 @248)
__global__ __launch_bounds__(256) void k_kpred(
    const float* __restrict__ b_lw, float* __restrict__ ws) {
  const int idx = blockIdx.x * 256 + threadIdx.x;
  if (idx >= 249 * 576) return;
  const int oc = idx / 576, p = idx % 576;
  const float* pp = ws + OFF_KPP;
  float s = b_lw[oc];
#pragma unroll
  for (int sl = 0; sl < 8; ++sl) s += pp[((unsigned)(sl * 249 + oc)) * 576u + p];
  int noc;
  if (oc < 160)      { noc = (oc % 20) * 8 + (oc / 20); }
  else if (oc < 168) { noc = oc; }
  else if (oc < 232) { const int t = oc - 168; noc = 168 + (t % 8) * 8 + (t / 8); }
  else               { noc = oc; }
  ws[OFF_KPT + (unsigned)p * 249u + noc] = s;
}

// ---------------- K5: x0 -> 40x40 (antialiased, padded 42x42) --------------
__global__ __launch_bounds__(256) void k_x0r(
    const float* __restrict__ x0, float* __restrict__ ws) {
  const int idx = blockIdx.x * 256 + threadIdx.x;  // 256*1764
  float* xr = ws + OFF_X0R;
  const int c = idx / 1764, r = idx % 1764;
  const int py = r / 42, px = r % 42;
  const int oy = py - 1, ox = px - 1;
  if (oy < 0 || oy >= 40 || ox < 0 || ox >= 40) { xr[idx] = 0.f; return; }
  float wy[8], wx[8];
  int iy0, ix0;
  {
    const float s = (oy + 0.5f) * 3.2f - 0.5f;
    iy0 = (int)floorf(s) - 3;
    float sw = 0.f;
#pragma unroll
    for (int a = 0; a < 8; ++a) {
      const int i = iy0 + a;
      float w = fmaxf(1.0f - fabsf((float)i - s) * 0.3125f, 0.f);
      if (i < 0 || i > 127) w = 0.f;
      wy[a] = w; sw += w;
    }
    const float inv = 1.0f / sw;
#pragma unroll
    for (int a = 0; a < 8; ++a) wy[a] *= inv;
  }
  {
    const float s = (ox + 0.5f) * 3.2f - 0.5f;
    ix0 = (int)floorf(s) - 3;
    float sw = 0.f;
#pragma unroll
    for (int a = 0; a < 8; ++a) {
      const int i = ix0 + a;
      float w = fmaxf(1.0f - fabsf((float)i - s) * 0.3125f, 0.f);
      if (i < 0 || i > 127) w = 0.f;
      wx[a] = w; sw += w;
    }
    const float inv = 1.0f / sw;
#pragma unroll
    for (int a = 0; a < 8; ++a) wx[a] *= inv;
  }
  float acc = 0.f;
#pragma unroll
  for (int a = 0; a < 8; ++a) {
    const int iy = min(max(iy0 + a, 0), 127);
    const float* row = x0 + c * 16384 + iy * 128;
#pragma unroll
    for (int bb = 0; bb < 8; ++bb) {
      const int ix = min(max(ix0 + bb, 0), 127);
      acc += wy[a] * wx[bb] * row[ix];
    }
  }
  xr[idx] = acc;
}

// ---------------- K6: 3x3 conv 256->80, 8-way channel split ----------------
__global__ __launch_bounds__(256) void k_cate(
    const float* __restrict__ w_cate, float* __restrict__ ws) {
  const int oc = blockIdx.x, tid = threadIdx.x;
  const int pb = blockIdx.y * 800;
  const int sl = blockIdx.z;
  const float* xr = ws + OFF_X0R;
  float* pp = ws + OFF_CPP + ((unsigned)(sl * 80 + oc)) * 1600u;
  const float* __restrict__ wb = w_cate + oc * 2304 + sl * 32 * 9;
  float a0 = 0.f, a1 = 0.f, a2 = 0.f, a3 = 0.f;
  const bool has3 = tid < 32;
  const int p0 = pb + tid, p1 = p0 + 256, p2 = p0 + 512;
  const int p3 = has3 ? p0 + 768 : p0;
  const int b0 = (p0 / 40) * 42 + (p0 % 40);
  const int b1 = (p1 / 40) * 42 + (p1 % 40);
  const int b2 = (p2 / 40) * 42 + (p2 % 40);
  const int b3 = (p3 / 40) * 42 + (p3 % 40);
  const float* xb0 = xr + sl * 32 * 1764;
#pragma unroll 2
  for (int c = 0; c < 32; ++c) {
    const float* xb = xb0 + c * 1764;
    const float* wc = wb + c * 9;
#pragma unroll
    for (int t = 0; t < 9; ++t) {
      const float w = wc[t];
      const int d = (t / 3) * 42 + (t % 3);
      a0 += w * xb[b0 + d];
      a1 += w * xb[b1 + d];
      a2 += w * xb[b2 + d];
      a3 += w * xb[b3 + d];
    }
  }
  pp[p0] = a0;
  pp[p1] = a1;
  pp[p2] = a2;
  if (has3) pp[p3] = a3;
}

// ---------------- K6b: reduce cate partials + bias + sigmoid ---------------
__global__ __launch_bounds__(256) void k_catered(
    const float* __restrict__ b_cate, float* __restrict__ ws) {
  const int idx = blockIdx.x * 256 + threadIdx.x;  // 128000
  const int oc = idx / 1600;
  const float* pp = ws + OFF_CPP;
  float s = b_cate[oc];
#pragma unroll
  for (int sl = 0; sl < 8; ++sl) s += pp[(unsigned)sl * 128000u + idx];
  ws[OFF_CATE + idx] = sigmoidf_(s);
}

// ---------------- K7: points_nms -> out tail -------------------------------
__global__ __launch_bounds__(256) void k_nms(
    const float* __restrict__ ws, float* __restrict__ out) {
  const int idx = blockIdx.x * 256 + threadIdx.x;  // 128000
  const float* cp = ws + OFF_CATE;
  const int r = idx % 1600, y = r / 40, x = r % 40;
  const float v = cp[idx];
  float m = v;
  if (y > 0 && x > 0) m = fmaxf(m, cp[idx - 41]);
  if (y > 0)          m = fmaxf(m, cp[idx - 40]);
  if (x > 0)          m = fmaxf(m, cp[idx - 1]);
  out[SEG_ELEMS + idx] = (m == v) ? v : 0.f;
}

// ---------------- K8 v3: dynamic MLP, feat + weights both in LDS -----------
// 256 thr, 2 px/thread, 512-px tile (40 KB) + 12 positions' weights (12 KB)
// = 53 KB LDS -> 3 blocks/CU. Grid (32,48) = 1536 = exactly 2 rounds.
// All weight reads are uniform-address ds_read_b128 broadcasts: zero per-lane
// address VALU, ~100cy LDS latency hidden under ~980cy of FMA per position.
#define POSB 12
__global__ __launch_bounds__(256, 4) void k_dyn(
    const float* __restrict__ ws, float* __restrict__ out) {
  __shared__ float fl[20][512];      // 40960 B
  __shared__ float wlds[POSB][252];  // 12096 B (252: keeps rows 16B-aligned)
  const int tid = threadIdx.x;
  const float* feat = ws + OFF_FEAT;
  const float* kpT = ws + OFF_KPT;
  const int pb = blockIdx.x * 512;
  const int n0 = blockIdx.y * POSB;
  // stage feat tile (coalesced float2 per thread per channel)
#pragma unroll
  for (int e = 0; e < 20; ++e) {
    const float2 v =
        *reinterpret_cast<const float2*>(feat + e * 16384 + pb + tid * 2);
    *reinterpret_cast<float2*>(&fl[e][tid * 2]) = v;
  }
  // stage POSB positions' weights (transposed layout from k_kpred)
#pragma unroll
  for (int np = 0; np < POSB; ++np) {
    if (tid < 249) wlds[np][tid] = kpT[(unsigned)(n0 + np) * 249u + tid];
  }
  __syncthreads();
#pragma unroll 1
  for (int np = 0; np < POSB; ++np) {
    const float* __restrict__ w = &wlds[np][0];
    // layer 1: 20 -> 8, relu
    float h1a[8], h1b[8];
    {
      const float4 ba = *reinterpret_cast<const float4*>(w + 160);
      const float4 bb = *reinterpret_cast<const float4*>(w + 164);
      h1a[0] = ba.x; h1a[1] = ba.y; h1a[2] = ba.z; h1a[3] = ba.w;
      h1a[4] = bb.x; h1a[5] = bb.y; h1a[6] = bb.z; h1a[7] = bb.w;
#pragma unroll
      for (int d = 0; d < 8; ++d) h1b[d] = h1a[d];
    }
#pragma unroll
    for (int e = 0; e < 20; ++e) {
      const float2 v = *reinterpret_cast<const float2*>(&fl[e][tid * 2]);
      const float4 wa = *reinterpret_cast<const float4*>(w + e * 8);
      const float4 wb = *reinterpret_cast<const float4*>(w + e * 8 + 4);
      h1a[0] += wa.x * v.x; h1b[0] += wa.x * v.y;
      h1a[1] += wa.y * v.x; h1b[1] += wa.y * v.y;
      h1a[2] += wa.z * v.x; h1b[2] += wa.z * v.y;
      h1a[3] += wa.w * v.x; h1b[3] += wa.w * v.y;
      h1a[4] += wb.x * v.x; h1b[4] += wb.x * v.y;
      h1a[5] += wb.y * v.x; h1b[5] += wb.y * v.y;
      h1a[6] += wb.z * v.x; h1b[6] += wb.z * v.y;
      h1a[7] += wb.w * v.x; h1b[7] += wb.w * v.y;
    }
#pragma unroll
    for (int d = 0; d < 8; ++d) {
      h1a[d] = fmaxf(h1a[d], 0.f);
      h1b[d] = fmaxf(h1b[d], 0.f);
    }
    // layer 2: 8 -> 8, relu (W1 as [e][d] at 168+e*8+d)
    float h2a[8], h2b[8];
    {
      const float4 ba = *reinterpret_cast<const float4*>(w + 232);
      const float4 bb = *reinterpret_cast<const float4*>(w + 236);
      h2a[0] = ba.x; h2a[1] = ba.y; h2a[2] = ba.z; h2a[3] = ba.w;
      h2a[4] = bb.x; h2a[5] = bb.y; h2a[6] = bb.z; h2a[7] = bb.w;
#pragma unroll
      for (int d = 0; d < 8; ++d) h2b[d] = h2a[d];
    }
#pragma unroll
    for (int e = 0; e < 8; ++e) {
      const float va = h1a[e], vb = h1b[e];
      const float4 wa = *reinterpret_cast<const float4*>(w + 168 + e * 8);
      const float4 wb = *reinterpret_cast<const float4*>(w + 168 + e * 8 + 4);
      h2a[0] += wa.x * va; h2b[0] += wa.x * vb;
      h2a[1] += wa.y * va; h2b[1] += wa.y * vb;
      h2a[2] += wa.z * va; h2b[2] += wa.z * vb;
      h2a[3] += wa.w * va; h2b[3] += wa.w * vb;
      h2a[4] += wb.x * va; h2b[4] += wb.x * vb;
      h2a[5] += wb.y * va; h2b[5] += wb.y * vb;
      h2a[6] += wb.z * va; h2b[6] += wb.z * vb;
      h2a[7] += wb.w * va; h2b[7] += wb.w * vb;
    }
    // layer 3: 8 -> 1, sigmoid
    float ma, mb;
    {
      const float4 wa = *reinterpret_cast<const float4*>(w + 240);
      const float4 wb = *reinterpret_cast<const float4*>(w + 244);
      const float b2 = w[248];
      ma = b2 + wa.x * fmaxf(h2a[0], 0.f) + wa.y * fmaxf(h2a[1], 0.f) +
           wa.z * fmaxf(h2a[2], 0.f) + wa.w * fmaxf(h2a[3], 0.f) +
           wb.x * fmaxf(h2a[4], 0.f) + wb.y * fmaxf(h2a[5], 0.f) +
           wb.z * fmaxf(h2a[6], 0.f) + wb.w * fmaxf(h2a[7], 0.f);
      mb = b2 + wa.x * fmaxf(h2b[0], 0.f) + wa.y * fmaxf(h2b[1], 0.f) +
           wa.z * fmaxf(h2b[2], 0.f) + wa.w * fmaxf(h2b[3], 0.f) +
           wb.x * fmaxf(h2b[4], 0.f) + wb.y * fmaxf(h2b[5], 0.f) +
           wb.z * fmaxf(h2b[6], 0.f) + wb.w * fmaxf(h2b[7], 0.f);
    }
    float2 rr;
    rr.x = sigmoidf_(ma);
    rr.y = sigmoidf_(mb);
    *reinterpret_cast<float2*>(
        out + (size_t)(n0 + np) * 16384 + pb + tid * 2) = rr;
  }
}

// ---------------------------------------------------------------------------
extern "C" void kernel_launch(void* const* d_in, const int* in_sizes, int n_in,
                              void* d_out, int out_size, void* d_ws, size_t ws_size,
                              hipStream_t stream) {
  const float* x0        = (const float*)d_in[0];
  const float* x1        = (const float*)d_in[1];
  const float* x2        = (const float*)d_in[2];
  const float* x3        = (const float*)d_in[3];
  const float* x4        = (const float*)d_in[4];
  const float* mask_feat = (const float*)d_in[5];
  const float* w_ctx     = (const float*)d_in[6];
  const float* b_ctx     = (const float*)d_in[7];
  const float* w_lw      = (const float*)d_in[8];
  const float* b_lw      = (const float*)d_in[9];
  const float* w_cate    = (const float*)d_in[10];
  const float* b_cate    = (const float*)d_in[11];
  float* out = (float*)d_out;
  float* ws  = (float*)d_ws;

  hipLaunchKernelGGL(k_gemm_ys, dim3(341), dim3(256), 0, stream,
                     x0, x1, x2, x3, x4, w_ctx, ws);
  hipLaunchKernelGGL(k_feat, dim3(1280), dim3(256), 0, stream,
                     mask_feat, b_ctx, ws);
  hipLaunchKernelGGL(k_kin, dim3(676), dim3(256), 0, stream, x2, ws);
  hipLaunchKernelGGL(k_kpconv, dim3(249, 8), dim3(256), 0, stream, w_lw, ws);
  hipLaunchKernelGGL(k_kpred, dim3(561), dim3(256), 0, stream, b_lw, ws);
  hipLaunchKernelGGL(k_x0r, dim3(1764), dim3(256), 0, stream, x0, ws);
  hipLaunchKernelGGL(k_cate, dim3(80, 2, 8), dim3(256), 0, stream, w_cate, ws);
  hipLaunchKernelGGL(k_catered, dim3(500), dim3(256), 0, stream, b_cate, ws);
  hipLaunchKernelGGL(k_nms, dim3(500), dim3(256), 0, stream, ws, out);
  hipLaunchKernelGGL(k_dyn, dim3(32, 48), dim3(256), 0, stream, ws, out);
}